// Round 2
// baseline (332.961 us; speedup 1.0000x reference)
//
#include <hip/hip_runtime.h>
#include <hip/hip_bf16.h>
#include <stdint.h>

// Problem: feats[8,1024,32,32]f32, conv_w[256,1024]f32, conv_b[256]f32,
// codebook[16384,256]f32 -> z_q[8,256,32,32]f32 (2097152) + loss scalar.
//
// Round-13 design:
//  - gemm2: back to 256-thr / i-tile-64 (round-11 shape; i-128 was -3%) with
//    an explicit 2-deep register software pipeline: fragments for ks+1 load
//    BEFORE the MFMAs of ks, so the ~200cy L2 latency of the codebook
//    A-stream hides under the MFMA cluster. Keeps round-12's bias-3.0 acc
//    init + paired v_max3_i32 fold.
//  - gemm1: BK=128 (16 barrier drains instead of 32)
//  - k_final split: k_argmin (idx+loss) + k_gather (LDS-staged coalesced
//    codebook gather)

typedef float f32x4 __attribute__((ext_vector_type(4)));
typedef float f32x16 __attribute__((ext_vector_type(16)));
typedef short s16x8 __attribute__((ext_vector_type(8)));

__device__ __forceinline__ void gl2lds16(const void* g, void* l) {
  __builtin_amdgcn_global_load_lds(
      (const __attribute__((address_space(1))) void*)g,
      (__attribute__((address_space(3))) void*)l, 16, 0, 0);
}

__device__ __forceinline__ unsigned short f2bf(float f) {
  unsigned u = __float_as_uint(f);
  u = u + 0x7FFFu + ((u >> 16) & 1u);
  return (unsigned short)(u >> 16);
}
__device__ __forceinline__ float bf2f(unsigned short u) {
  return __uint_as_float(((unsigned)u) << 16);
}

__device__ __forceinline__ ushort4 cvt4(float4 v) {
  ushort4 o;
  o.x = f2bf(v.x); o.y = f2bf(v.y); o.z = f2bf(v.z); o.w = f2bf(v.w);
  return o;
}

// Fused prep, 2432 blocks x 256 thr.
// [0,256):    codebook -> cbs in 32x32x16 A-fragment order. Block jt = 64 j.
//             fl = lp*256+t in [0,2048) maps [ks 16][fr 2][lane 64]:
//             lane holds A[j=jt*64+fr*32+(lane&31)][k=ks*16+(lane>>5)*8 ..+8]
// [256,384):  conv_w -> W2 bf16, 8 elem/thread
// [384,2432): feats [8][1024 c][1024 s] -> featsT bf16 [8192 i][1024 c]
__global__ void k_prep(const float* __restrict__ cbk, const float* __restrict__ Wsrc,
                       const float* __restrict__ feats,
                       unsigned short* __restrict__ cbs, unsigned short* __restrict__ W2,
                       unsigned short* __restrict__ At, float* __restrict__ lossw) {
  __shared__ float tile[64][65];
  int blk = blockIdx.x, t = threadIdx.x;
  if (blk == 0 && t < 2) ((int*)lossw)[t] = 0;
  if (blk < 256) {
    int jt = blk;
    #pragma unroll
    for (int lp = 0; lp < 8; ++lp) {
      int fl = lp * 256 + t;
      int ks = fl >> 7, fr = (fl >> 6) & 1, lane = fl & 63;
      int j = jt * 64 + fr * 32 + (lane & 31);
      int k = ks * 16 + (lane >> 5) * 8;
      const float* src = cbk + (size_t)j * 256 + k;
      float4 v0 = *(const float4*)(src);
      float4 v1 = *(const float4*)(src + 4);
      unsigned short* dst = cbs + ((size_t)jt * 2048 + fl) * 8;
      *(ushort4*)(dst) = cvt4(v0);
      *(ushort4*)(dst + 4) = cvt4(v1);
    }
  } else if (blk < 384) {
    size_t base = (size_t)(blk - 256) * 2048 + t * 8;
    float4 v0 = *(const float4*)(Wsrc + base);
    float4 v1 = *(const float4*)(Wsrc + base + 4);
    *(ushort4*)(W2 + base) = cvt4(v0);
    *(ushort4*)(W2 + base + 4) = cvt4(v1);
  } else {
    int id = blk - 384;
    int b = id >> 8, c0 = ((id >> 4) & 15) * 64, s0 = (id & 15) * 64;
    int tc = t >> 4, ts = (t & 15) * 4;
    #pragma unroll
    for (int k = 0; k < 4; ++k) {
      float4 v = *(const float4*)(feats + ((size_t)b * 1024 + c0 + tc + k * 16) * 1024 + s0 + ts);
      tile[tc + k * 16][ts] = v.x;
      tile[tc + k * 16][ts + 1] = v.y;
      tile[tc + k * 16][ts + 2] = v.z;
      tile[tc + k * 16][ts + 3] = v.w;
    }
    __syncthreads();
    #pragma unroll
    for (int k = 0; k < 4; ++k) {
      int sr = tc + k * 16;
      float4 v;
      v.x = tile[ts][sr]; v.y = tile[ts + 1][sr];
      v.z = tile[ts + 2][sr]; v.w = tile[ts + 3][sr];
      *(ushort4*)(At + (size_t)(b * 1024 + s0 + sr) * 1024 + c0 + ts) = cvt4(v);
    }
  }
}

// GEMM1: z[i][e] = sum_c feats[i][c]*W[e][c] + b[e] (K=1024 bf16) -> zb [i][256].
// BM=BN=64, BK=128 (8 kt iterations, 16 barrier drains), 4 waves 2x2
// (wave 32x32), grid (4,128). LDS 2 x 16 KB.
__global__ __launch_bounds__(256, 2)
void k_gemm1(const unsigned short* __restrict__ At, const unsigned short* __restrict__ Bw,
             const float* __restrict__ bias, unsigned short* __restrict__ zb) {
  __shared__ __align__(16) uint8_t lds[2048 * 16];
  uint8_t* ldsA = lds;
  uint8_t* ldsB = lds + 1024 * 16;
  const int t = threadIdx.x, w = t >> 6, l = t & 63;
  const int wy = w >> 1, wx = w & 1, l15 = l & 15, q = l >> 4;
  const int ib = blockIdx.y * 64, eb = blockIdx.x * 64;
  f32x4 acc[2][2] = {};
  for (int kt = 0; kt < 8; ++kt) {
    int c0 = kt * 128;
    __syncthreads();
    #pragma unroll
    for (int r = 0; r < 4; ++r) {
      int P = t + 256 * r;  // kp = P>>6 (0..15), m = P&63; LDS layout [kp][m]
      gl2lds16(At + (size_t)(ib + (P & 63)) * 1024 + c0 + (P >> 6) * 8, ldsA + P * 16);
    }
    #pragma unroll
    for (int r = 0; r < 4; ++r) {
      int P = t + 256 * r;
      gl2lds16(Bw + (size_t)(eb + (P & 63)) * 1024 + c0 + (P >> 6) * 8, ldsB + P * 16);
    }
    __syncthreads();
    #pragma unroll
    for (int s = 0; s < 4; ++s) {
      s16x8 a[2], b[2];
      #pragma unroll
      for (int fr = 0; fr < 2; ++fr)
        a[fr] = *(const s16x8*)(ldsA + ((s * 4 + q) * 64 + wy * 32 + fr * 16 + l15) * 16);
      #pragma unroll
      for (int fc = 0; fc < 2; ++fc)
        b[fc] = *(const s16x8*)(ldsB + ((s * 4 + q) * 64 + wx * 32 + fc * 16 + l15) * 16);
      #pragma unroll
      for (int fr = 0; fr < 2; ++fr)
        #pragma unroll
        for (int fc = 0; fc < 2; ++fc)
          acc[fr][fc] = __builtin_amdgcn_mfma_f32_16x16x32_bf16(a[fr], b[fc], acc[fr][fc], 0, 0, 0);
    }
  }
  #pragma unroll
  for (int fc = 0; fc < 2; ++fc) {
    int e = eb + wx * 32 + fc * 16 + l15;
    float bv = bias[e];
    #pragma unroll
    for (int fr = 0; fr < 2; ++fr)
      #pragma unroll
      for (int r = 0; r < 4; ++r) {
        int i = ib + wy * 32 + fr * 16 + q * 4 + r;
        zb[(size_t)i * 256 + e] = f2bf(acc[fr][fc][r] + bv);
      }
  }
}

// GEMM2 + argmax, 32x32x16 j-stream. A = cbs (fragment order),
// B = zb [8192 i][256]. 256 thr / 4 waves, i-tile 64 (32 KB LDS, 1 barrier).
// Wave tile 64j x 64i (acc 64 VGPR); wave w streams jtile = bx*8 + js*4 + w.
// grid (32 jsplit, 128 ib), XCD = bx%8 pinned. launch_bounds(256,4).
// Inner loop: explicit 2-deep register pipeline — a/b fragments for ks+1
// issue BEFORE the 4 MFMAs of ks (static double buffers, full unroll), so
// the ~200cy L2 latency of the A-stream overlaps the MFMA cluster instead
// of serializing with it.
// Bias 3.0 pre-loaded in acc (MFMA C-chain absorbs it).
// Fold: p = (bits(acc)<<14) + (16383-j); paired -> v_max3_i32.
__global__ __launch_bounds__(256, 4)
void k_gemm2(const unsigned short* __restrict__ cbs, const unsigned short* __restrict__ zb,
             int* __restrict__ cand) {
  __shared__ __align__(16) uint8_t ldsB[2048 * 16];  // 32 KB: [kp 32][i 64][8 bf16]
  __shared__ int csh[4][64];
  const int t = threadIdx.x, w = t >> 6, l = t & 63;
  const int l31 = l & 31, h = l >> 5;
  const int ib = blockIdx.y * 64;
  // stage zb tile once: packet P -> i = P&63, kp = P>>6
  #pragma unroll
  for (int r = 0; r < 8; ++r) {
    int P = t + 256 * r;
    gl2lds16(zb + (size_t)(ib + (P & 63)) * 256 + (P >> 6) * 8, ldsB + P * 16);
  }
  int rbest[2];
  rbest[0] = rbest[1] = (int)0x80000000;
  __syncthreads();
  const uint8_t* bbase = ldsB + (h * 64 + l31) * 16;  // + ks*2048 + fc*512
  #pragma unroll 1
  for (int js = 0; js < 2; ++js) {
    const int jtile = blockIdx.x * 8 + js * 4 + w;  // 64-j tile index
    const int jw = jtile * 64;
    const uint8_t* abase = (const uint8_t*)cbs + (size_t)jtile * 32768 + l * 16;
    f32x16 acc[2][2];  // [fr j-half][fc i-half], pre-biased at 3.0
    #pragma unroll
    for (int fr = 0; fr < 2; ++fr)
      #pragma unroll
      for (int fc = 0; fc < 2; ++fc)
        #pragma unroll
        for (int rg = 0; rg < 16; ++rg)
          acc[fr][fc][rg] = 3.0f;
    // 2-deep pipelined fragment buffers (all indices static after unroll)
    s16x8 a[2][2], b[2][2];
    a[0][0] = *(const s16x8*)(abase);
    a[0][1] = *(const s16x8*)(abase + 1024);
    b[0][0] = *(const s16x8*)(bbase);
    b[0][1] = *(const s16x8*)(bbase + 512);
    #pragma unroll
    for (int ks = 0; ks < 16; ++ks) {
      const int cur = ks & 1, nxt = cur ^ 1;
      if (ks < 15) {
        const uint8_t* ap = abase + (ks + 1) * 2048;
        const uint8_t* bp = bbase + (ks + 1) * 2048;
        a[nxt][0] = *(const s16x8*)(ap);
        a[nxt][1] = *(const s16x8*)(ap + 1024);
        b[nxt][0] = *(const s16x8*)(bp);
        b[nxt][1] = *(const s16x8*)(bp + 512);
      }
      #pragma unroll
      for (int fr = 0; fr < 2; ++fr)
        #pragma unroll
        for (int fc = 0; fc < 2; ++fc)
          acc[fr][fc] = __builtin_amdgcn_mfma_f32_32x32x16_bf16(a[cur][fr], b[cur][fc], acc[fr][fc], 0, 0, 0);
    }
    // fold: j = jw + fr*32 + (rg&3) + 8*(rg>>2) + 4*h ; i = ib + fc*32 + l31
    const int encb = 16383 - (jw + 4 * h);
    #pragma unroll
    for (int fc = 0; fc < 2; ++fc) {
      int bb = rbest[fc];
      #pragma unroll
      for (int fr = 0; fr < 2; ++fr) {
        const int e1 = encb - fr * 32;
        #pragma unroll
        for (int rg = 0; rg < 16; rg += 2) {
          int e0 = e1 - ((rg & 3) + 8 * (rg >> 2));  // rg even; rg+1 -> e0-1
          int p0 = (int)(((unsigned)__float_as_int(acc[fr][fc][rg]) << 14) + (unsigned)e0);
          int p1 = (int)(((unsigned)__float_as_int(acc[fr][fc][rg + 1]) << 14) + (unsigned)(e0 - 1));
          bb = max(max(p0, p1), bb);  // v_max3_i32
        }
      }
      rbest[fc] = bb;
    }
  }
  // reduce over h (lane>>5 halves hold disjoint j, same i)
  #pragma unroll
  for (int fc = 0; fc < 2; ++fc) {
    int bb = max(rbest[fc], __shfl_xor(rbest[fc], 32, 64));
    if (l < 32) csh[w][fc * 32 + l31] = bb;
  }
  __syncthreads();
  if (t < 64) {
    int m0 = max(max(csh[0][t], csh[1][t]), max(csh[2][t], csh[3][t]));
    cand[(size_t)blockIdx.x * 8192 + ib + t] = m0;
  }
}

// argmin + loss. 128 blocks x 256 thr; block = 64 rows.
// dist_i = ||z_i||^2 - (p>>14)*2^-20. Last block writes the loss scalar.
__global__ void k_argmin(const unsigned short* __restrict__ zb, const int* __restrict__ cand,
                         int* __restrict__ idx, float* __restrict__ lossw,
                         float* __restrict__ out) {
  __shared__ float ps[4];
  int blk = blockIdx.x, t = threadIdx.x;
  int row = t >> 2, c = t & 3;
  int gi = blk * 64 + row;
  // ||z||^2 partial over 64 bf16 elems
  const unsigned short* zrow = zb + (size_t)gi * 256 + c * 64;
  float ss = 0.0f;
  #pragma unroll
  for (int k = 0; k < 64; k += 4) {
    ushort4 v = *(const ushort4*)(zrow + k);
    float a0 = bf2f(v.x), a1 = bf2f(v.y), a2 = bf2f(v.z), a3 = bf2f(v.w);
    ss += a0 * a0 + a1 * a1 + a2 * a2 + a3 * a3;
  }
  // argmax over 32 jsplit partials
  int best = (int)0x80000000;
  #pragma unroll
  for (int k = 0; k < 8; ++k) {
    int v = cand[(size_t)(c + 4 * k) * 8192 + gi];
    best = v > best ? v : best;
  }
  best = max(best, __shfl_xor(best, 1, 64));
  best = max(best, __shfl_xor(best, 2, 64));
  ss += __shfl_xor(ss, 1, 64);
  ss += __shfl_xor(ss, 2, 64);
  float dist = 0.0f;
  if (c == 0) {
    idx[gi] = 16383 - (best & 0x3FFF);
    dist = ss - (float)(best >> 14) * (1.0f / 1048576.0f);  // 2*score
  }
  float v = dist;
  #pragma unroll
  for (int m = 32; m; m >>= 1) v += __shfl_down(v, m, 64);
  if ((t & 63) == 0) ps[t >> 6] = v;
  __syncthreads();
  if (t == 0) {
    float part = ps[0] + ps[1] + ps[2] + ps[3];
    atomicAdd(lossw, part);
    __threadfence();
    int cnt = atomicAdd((int*)lossw + 1, 1);
    if (cnt == 127) {
      __threadfence();
      float total = atomicAdd(lossw, 0.0f);
      out[2097152] = 1.25f * total * (1.0f / 2097152.0f);
    }
  }
}

// Output gather, LDS-staged for coalescing both sides. 256 blocks x 256 thr;
// block = (b, s0) covering 32 rows. Phase A: wave reads codebook rows as
// 256B bursts -> tile[32][257] (conflict-free b32 writes). Phase B: writes
// out[b][e][s0+sl] in 128B contiguous runs, LDS reads conflict-free (pad 257).
__global__ void k_gather(const float* __restrict__ cbk, const int* __restrict__ idx,
                         float* __restrict__ out) {
  __shared__ float tile[32][257];
  __shared__ int lidx[32];
  int blk = blockIdx.x, t = threadIdx.x;
  int b = blk >> 5, s0 = (blk & 31) * 32;
  if (t < 32) lidx[t] = idx[b * 1024 + s0 + t];
  __syncthreads();
  int w = t >> 6, l = t & 63;
  #pragma unroll
  for (int rr = 0; rr < 8; ++rr) {
    int r = w * 8 + rr;
    const float* src = cbk + (size_t)lidx[r] * 256;
    #pragma unroll
    for (int k = 0; k < 4; ++k)
      tile[r][l + 64 * k] = src[l + 64 * k];
  }
  __syncthreads();
  int sl = t & 31, eg = t >> 5;  // eg 0..7
  size_t ob = (size_t)b * 262144 + s0 + sl;
  #pragma unroll
  for (int k = 0; k < 32; ++k) {
    int e = eg + 8 * k;
    out[ob + (size_t)e * 1024] = tile[sl][e];
  }
}

extern "C" void kernel_launch(void* const* d_in, const int* in_sizes, int n_in,
                              void* d_out, int out_size, void* d_ws, size_t ws_size,
                              hipStream_t stream) {
  const float* feats  = (const float*)d_in[0];
  const float* conv_w = (const float*)d_in[1];
  const float* conv_b = (const float*)d_in[2];
  const float* cbk    = (const float*)d_in[3];
  float* out = (float*)d_out;
  char* ws = (char*)d_ws;
  // workspace layout (bytes), ~31 MB total
  unsigned short* featsT = (unsigned short*)(ws);                  // 16,777,216
  unsigned short* W2     = (unsigned short*)(ws + 16777216);       //    524,288
  unsigned short* cbs    = (unsigned short*)(ws + 17301504);       //  8,388,608
  unsigned short* zb     = (unsigned short*)(ws + 25690112);       //  4,194,304
  int*            cand   = (int*)(ws + 29884416);                  //  1,048,576
  int*            idx    = (int*)(ws + 30932992);                  //     32,768
  float*          lossw  = (float*)(ws + 30965760);                //        256

  k_prep<<<2432, 256, 0, stream>>>(cbk, conv_w, feats, cbs, W2, featsT, lossw);
  k_gemm1<<<dim3(4, 128), 256, 0, stream>>>(featsT, W2, conv_b, zb);
  k_gemm2<<<dim3(32, 128), 256, 0, stream>>>(cbs, zb, cand);
  k_argmin<<<128, 256, 0, stream>>>(zb, cand, idx, lossw, out);
  k_gather<<<256, 256, 0, stream>>>(cbk, idx, out);
}

// Round 3
// 319.485 us; speedup vs baseline: 1.0422x; 1.0422x over previous
//
#include <hip/hip_runtime.h>
#include <hip/hip_bf16.h>
#include <stdint.h>

// Problem: feats[8,1024,32,32]f32, conv_w[256,1024]f32, conv_b[256]f32,
// codebook[16384,256]f32 -> z_q[8,256,32,32]f32 (2097152) + loss scalar.
//
// Round-14 design:
//  - gemm2: 256-thr / i-tile-64 (r11 shape) + software pipeline SIZED TO FIT:
//    3-buffer rotation on the global A-stream (depth-2 ~= 192cy coverage) +
//    2-buffer on LDS B (depth-1). Frags are 4 VGPR each (s16x8 = 16B), so
//    total ~130 regs -> launch_bounds(256,3) (~170 cap). r13 spilled because
//    (256,4)'s 128-reg cap couldn't hold the double buffers -> 419 MB scratch.
//    Keeps bias-3.0 acc init + paired v_max3_i32 fold.
//  - gemm1: BK=128 (16 barrier drains instead of 32)
//  - k_final split: k_argmin (idx+loss) + k_gather (LDS-staged coalesced
//    codebook gather)

typedef float f32x4 __attribute__((ext_vector_type(4)));
typedef float f32x16 __attribute__((ext_vector_type(16)));
typedef short s16x8 __attribute__((ext_vector_type(8)));

__device__ __forceinline__ void gl2lds16(const void* g, void* l) {
  __builtin_amdgcn_global_load_lds(
      (const __attribute__((address_space(1))) void*)g,
      (__attribute__((address_space(3))) void*)l, 16, 0, 0);
}

__device__ __forceinline__ unsigned short f2bf(float f) {
  unsigned u = __float_as_uint(f);
  u = u + 0x7FFFu + ((u >> 16) & 1u);
  return (unsigned short)(u >> 16);
}
__device__ __forceinline__ float bf2f(unsigned short u) {
  return __uint_as_float(((unsigned)u) << 16);
}

__device__ __forceinline__ ushort4 cvt4(float4 v) {
  ushort4 o;
  o.x = f2bf(v.x); o.y = f2bf(v.y); o.z = f2bf(v.z); o.w = f2bf(v.w);
  return o;
}

// Fused prep, 2432 blocks x 256 thr.
// [0,256):    codebook -> cbs in 32x32x16 A-fragment order. Block jt = 64 j.
//             fl = lp*256+t in [0,2048) maps [ks 16][fr 2][lane 64]:
//             lane holds A[j=jt*64+fr*32+(lane&31)][k=ks*16+(lane>>5)*8 ..+8]
// [256,384):  conv_w -> W2 bf16, 8 elem/thread
// [384,2432): feats [8][1024 c][1024 s] -> featsT bf16 [8192 i][1024 c]
__global__ void k_prep(const float* __restrict__ cbk, const float* __restrict__ Wsrc,
                       const float* __restrict__ feats,
                       unsigned short* __restrict__ cbs, unsigned short* __restrict__ W2,
                       unsigned short* __restrict__ At, float* __restrict__ lossw) {
  __shared__ float tile[64][65];
  int blk = blockIdx.x, t = threadIdx.x;
  if (blk == 0 && t < 2) ((int*)lossw)[t] = 0;
  if (blk < 256) {
    int jt = blk;
    #pragma unroll
    for (int lp = 0; lp < 8; ++lp) {
      int fl = lp * 256 + t;
      int ks = fl >> 7, fr = (fl >> 6) & 1, lane = fl & 63;
      int j = jt * 64 + fr * 32 + (lane & 31);
      int k = ks * 16 + (lane >> 5) * 8;
      const float* src = cbk + (size_t)j * 256 + k;
      float4 v0 = *(const float4*)(src);
      float4 v1 = *(const float4*)(src + 4);
      unsigned short* dst = cbs + ((size_t)jt * 2048 + fl) * 8;
      *(ushort4*)(dst) = cvt4(v0);
      *(ushort4*)(dst + 4) = cvt4(v1);
    }
  } else if (blk < 384) {
    size_t base = (size_t)(blk - 256) * 2048 + t * 8;
    float4 v0 = *(const float4*)(Wsrc + base);
    float4 v1 = *(const float4*)(Wsrc + base + 4);
    *(ushort4*)(W2 + base) = cvt4(v0);
    *(ushort4*)(W2 + base + 4) = cvt4(v1);
  } else {
    int id = blk - 384;
    int b = id >> 8, c0 = ((id >> 4) & 15) * 64, s0 = (id & 15) * 64;
    int tc = t >> 4, ts = (t & 15) * 4;
    #pragma unroll
    for (int k = 0; k < 4; ++k) {
      float4 v = *(const float4*)(feats + ((size_t)b * 1024 + c0 + tc + k * 16) * 1024 + s0 + ts);
      tile[tc + k * 16][ts] = v.x;
      tile[tc + k * 16][ts + 1] = v.y;
      tile[tc + k * 16][ts + 2] = v.z;
      tile[tc + k * 16][ts + 3] = v.w;
    }
    __syncthreads();
    #pragma unroll
    for (int k = 0; k < 4; ++k) {
      int sr = tc + k * 16;
      float4 v;
      v.x = tile[ts][sr]; v.y = tile[ts + 1][sr];
      v.z = tile[ts + 2][sr]; v.w = tile[ts + 3][sr];
      *(ushort4*)(At + (size_t)(b * 1024 + s0 + sr) * 1024 + c0 + ts) = cvt4(v);
    }
  }
}

// GEMM1: z[i][e] = sum_c feats[i][c]*W[e][c] + b[e] (K=1024 bf16) -> zb [i][256].
// BM=BN=64, BK=128 (8 kt iterations, 16 barrier drains), 4 waves 2x2
// (wave 32x32), grid (4,128). LDS 2 x 16 KB.
__global__ __launch_bounds__(256, 2)
void k_gemm1(const unsigned short* __restrict__ At, const unsigned short* __restrict__ Bw,
             const float* __restrict__ bias, unsigned short* __restrict__ zb) {
  __shared__ __align__(16) uint8_t lds[2048 * 16];
  uint8_t* ldsA = lds;
  uint8_t* ldsB = lds + 1024 * 16;
  const int t = threadIdx.x, w = t >> 6, l = t & 63;
  const int wy = w >> 1, wx = w & 1, l15 = l & 15, q = l >> 4;
  const int ib = blockIdx.y * 64, eb = blockIdx.x * 64;
  f32x4 acc[2][2] = {};
  for (int kt = 0; kt < 8; ++kt) {
    int c0 = kt * 128;
    __syncthreads();
    #pragma unroll
    for (int r = 0; r < 4; ++r) {
      int P = t + 256 * r;  // kp = P>>6 (0..15), m = P&63; LDS layout [kp][m]
      gl2lds16(At + (size_t)(ib + (P & 63)) * 1024 + c0 + (P >> 6) * 8, ldsA + P * 16);
    }
    #pragma unroll
    for (int r = 0; r < 4; ++r) {
      int P = t + 256 * r;
      gl2lds16(Bw + (size_t)(eb + (P & 63)) * 1024 + c0 + (P >> 6) * 8, ldsB + P * 16);
    }
    __syncthreads();
    #pragma unroll
    for (int s = 0; s < 4; ++s) {
      s16x8 a[2], b[2];
      #pragma unroll
      for (int fr = 0; fr < 2; ++fr)
        a[fr] = *(const s16x8*)(ldsA + ((s * 4 + q) * 64 + wy * 32 + fr * 16 + l15) * 16);
      #pragma unroll
      for (int fc = 0; fc < 2; ++fc)
        b[fc] = *(const s16x8*)(ldsB + ((s * 4 + q) * 64 + wx * 32 + fc * 16 + l15) * 16);
      #pragma unroll
      for (int fr = 0; fr < 2; ++fr)
        #pragma unroll
        for (int fc = 0; fc < 2; ++fc)
          acc[fr][fc] = __builtin_amdgcn_mfma_f32_16x16x32_bf16(a[fr], b[fc], acc[fr][fc], 0, 0, 0);
    }
  }
  #pragma unroll
  for (int fc = 0; fc < 2; ++fc) {
    int e = eb + wx * 32 + fc * 16 + l15;
    float bv = bias[e];
    #pragma unroll
    for (int fr = 0; fr < 2; ++fr)
      #pragma unroll
      for (int r = 0; r < 4; ++r) {
        int i = ib + wy * 32 + fr * 16 + q * 4 + r;
        zb[(size_t)i * 256 + e] = f2bf(acc[fr][fc][r] + bv);
      }
  }
}

// GEMM2 + argmax, 32x32x16 j-stream. A = cbs (fragment order),
// B = zb [8192 i][256]. 256 thr / 4 waves, i-tile 64 (32 KB LDS, 1 barrier).
// Wave tile 64j x 64i (acc 64 VGPR); wave w streams jtile = bx*8 + js*4 + w.
// grid (32 jsplit, 128 ib), XCD = bx%8 pinned.
// Software pipeline, sized to fit launch_bounds(256,3):
//   A (global, ~200cy L2): 3-buffer rotation, loads for ks+2 issue first.
//   B (LDS, ~120cy):       2-buffer, loads for ks+1 issue second.
//   MFMAs for ks issue last. Frags are 4 VGPR each; total ~130 regs.
// Bias 3.0 pre-loaded in acc (MFMA C-chain absorbs it).
// Fold: p = (bits(acc)<<14) + (16383-j); paired -> v_max3_i32.
__global__ __launch_bounds__(256, 3)
void k_gemm2(const unsigned short* __restrict__ cbs, const unsigned short* __restrict__ zb,
             int* __restrict__ cand) {
  __shared__ __align__(16) uint8_t ldsB[2048 * 16];  // 32 KB: [kp 32][i 64][8 bf16]
  __shared__ int csh[4][64];
  const int t = threadIdx.x, w = t >> 6, l = t & 63;
  const int l31 = l & 31, h = l >> 5;
  const int ib = blockIdx.y * 64;
  // stage zb tile once: packet P -> i = P&63, kp = P>>6
  #pragma unroll
  for (int r = 0; r < 8; ++r) {
    int P = t + 256 * r;
    gl2lds16(zb + (size_t)(ib + (P & 63)) * 256 + (P >> 6) * 8, ldsB + P * 16);
  }
  int rbest[2];
  rbest[0] = rbest[1] = (int)0x80000000;
  __syncthreads();
  const uint8_t* bbase = ldsB + (h * 64 + l31) * 16;  // + ks*2048 + fc*512
  #pragma unroll 1
  for (int js = 0; js < 2; ++js) {
    const int jtile = blockIdx.x * 8 + js * 4 + w;  // 64-j tile index
    const int jw = jtile * 64;
    const uint8_t* abase = (const uint8_t*)cbs + (size_t)jtile * 32768 + l * 16;
    f32x16 acc[2][2];  // [fr j-half][fc i-half], pre-biased at 3.0
    #pragma unroll
    for (int fr = 0; fr < 2; ++fr)
      #pragma unroll
      for (int fc = 0; fc < 2; ++fc)
        #pragma unroll
        for (int rg = 0; rg < 16; ++rg)
          acc[fr][fc][rg] = 3.0f;
    // pipelined fragment buffers (all indices static after full unroll)
    s16x8 a[3][2], b[2][2];
    #pragma unroll
    for (int fr = 0; fr < 2; ++fr) {
      a[0][fr] = *(const s16x8*)(abase + fr * 1024);
      a[1][fr] = *(const s16x8*)(abase + 2048 + fr * 1024);
    }
    #pragma unroll
    for (int fc = 0; fc < 2; ++fc)
      b[0][fc] = *(const s16x8*)(bbase + fc * 512);
    #pragma unroll
    for (int ks = 0; ks < 16; ++ks) {
      // 1) A prefetch for ks+2 (global; in flight across ~2 iterations)
      if (ks < 14) {
        const uint8_t* ap = abase + (ks + 2) * 2048;
        #pragma unroll
        for (int fr = 0; fr < 2; ++fr)
          a[(ks + 2) % 3][fr] = *(const s16x8*)(ap + fr * 1024);
      }
      // 2) B prefetch for ks+1 (LDS)
      if (ks < 15) {
        const uint8_t* bp = bbase + (ks + 1) * 2048;
        #pragma unroll
        for (int fc = 0; fc < 2; ++fc)
          b[(ks + 1) & 1][fc] = *(const s16x8*)(bp + fc * 512);
      }
      // 3) MFMAs for ks
      #pragma unroll
      for (int fr = 0; fr < 2; ++fr)
        #pragma unroll
        for (int fc = 0; fc < 2; ++fc)
          acc[fr][fc] = __builtin_amdgcn_mfma_f32_32x32x16_bf16(a[ks % 3][fr], b[ks & 1][fc], acc[fr][fc], 0, 0, 0);
    }
    // fold: j = jw + fr*32 + (rg&3) + 8*(rg>>2) + 4*h ; i = ib + fc*32 + l31
    const int encb = 16383 - (jw + 4 * h);
    #pragma unroll
    for (int fc = 0; fc < 2; ++fc) {
      int bb = rbest[fc];
      #pragma unroll
      for (int fr = 0; fr < 2; ++fr) {
        const int e1 = encb - fr * 32;
        #pragma unroll
        for (int rg = 0; rg < 16; rg += 2) {
          int e0 = e1 - ((rg & 3) + 8 * (rg >> 2));  // rg even; rg+1 -> e0-1
          int p0 = (int)(((unsigned)__float_as_int(acc[fr][fc][rg]) << 14) + (unsigned)e0);
          int p1 = (int)(((unsigned)__float_as_int(acc[fr][fc][rg + 1]) << 14) + (unsigned)(e0 - 1));
          bb = max(max(p0, p1), bb);  // v_max3_i32
        }
      }
      rbest[fc] = bb;
    }
  }
  // reduce over h (lane>>5 halves hold disjoint j, same i)
  #pragma unroll
  for (int fc = 0; fc < 2; ++fc) {
    int bb = max(rbest[fc], __shfl_xor(rbest[fc], 32, 64));
    if (l < 32) csh[w][fc * 32 + l31] = bb;
  }
  __syncthreads();
  if (t < 64) {
    int m0 = max(max(csh[0][t], csh[1][t]), max(csh[2][t], csh[3][t]));
    cand[(size_t)blockIdx.x * 8192 + ib + t] = m0;
  }
}

// argmin + loss. 128 blocks x 256 thr; block = 64 rows.
// dist_i = ||z_i||^2 - (p>>14)*2^-20. Last block writes the loss scalar.
__global__ void k_argmin(const unsigned short* __restrict__ zb, const int* __restrict__ cand,
                         int* __restrict__ idx, float* __restrict__ lossw,
                         float* __restrict__ out) {
  __shared__ float ps[4];
  int blk = blockIdx.x, t = threadIdx.x;
  int row = t >> 2, c = t & 3;
  int gi = blk * 64 + row;
  // ||z||^2 partial over 64 bf16 elems
  const unsigned short* zrow = zb + (size_t)gi * 256 + c * 64;
  float ss = 0.0f;
  #pragma unroll
  for (int k = 0; k < 64; k += 4) {
    ushort4 v = *(const ushort4*)(zrow + k);
    float a0 = bf2f(v.x), a1 = bf2f(v.y), a2 = bf2f(v.z), a3 = bf2f(v.w);
    ss += a0 * a0 + a1 * a1 + a2 * a2 + a3 * a3;
  }
  // argmax over 32 jsplit partials
  int best = (int)0x80000000;
  #pragma unroll
  for (int k = 0; k < 8; ++k) {
    int v = cand[(size_t)(c + 4 * k) * 8192 + gi];
    best = v > best ? v : best;
  }
  best = max(best, __shfl_xor(best, 1, 64));
  best = max(best, __shfl_xor(best, 2, 64));
  ss += __shfl_xor(ss, 1, 64);
  ss += __shfl_xor(ss, 2, 64);
  float dist = 0.0f;
  if (c == 0) {
    idx[gi] = 16383 - (best & 0x3FFF);
    dist = ss - (float)(best >> 14) * (1.0f / 1048576.0f);  // 2*score
  }
  float v = dist;
  #pragma unroll
  for (int m = 32; m; m >>= 1) v += __shfl_down(v, m, 64);
  if ((t & 63) == 0) ps[t >> 6] = v;
  __syncthreads();
  if (t == 0) {
    float part = ps[0] + ps[1] + ps[2] + ps[3];
    atomicAdd(lossw, part);
    __threadfence();
    int cnt = atomicAdd((int*)lossw + 1, 1);
    if (cnt == 127) {
      __threadfence();
      float total = atomicAdd(lossw, 0.0f);
      out[2097152] = 1.25f * total * (1.0f / 2097152.0f);
    }
  }
}

// Output gather, LDS-staged for coalescing both sides. 256 blocks x 256 thr;
// block = (b, s0) covering 32 rows. Phase A: wave reads codebook rows as
// 256B bursts -> tile[32][257] (conflict-free b32 writes). Phase B: writes
// out[b][e][s0+sl] in 128B contiguous runs, LDS reads conflict-free (pad 257).
__global__ void k_gather(const float* __restrict__ cbk, const int* __restrict__ idx,
                         float* __restrict__ out) {
  __shared__ float tile[32][257];
  __shared__ int lidx[32];
  int blk = blockIdx.x, t = threadIdx.x;
  int b = blk >> 5, s0 = (blk & 31) * 32;
  if (t < 32) lidx[t] = idx[b * 1024 + s0 + t];
  __syncthreads();
  int w = t >> 6, l = t & 63;
  #pragma unroll
  for (int rr = 0; rr < 8; ++rr) {
    int r = w * 8 + rr;
    const float* src = cbk + (size_t)lidx[r] * 256;
    #pragma unroll
    for (int k = 0; k < 4; ++k)
      tile[r][l + 64 * k] = src[l + 64 * k];
  }
  __syncthreads();
  int sl = t & 31, eg = t >> 5;  // eg 0..7
  size_t ob = (size_t)b * 262144 + s0 + sl;
  #pragma unroll
  for (int k = 0; k < 32; ++k) {
    int e = eg + 8 * k;
    out[ob + (size_t)e * 1024] = tile[sl][e];
  }
}

extern "C" void kernel_launch(void* const* d_in, const int* in_sizes, int n_in,
                              void* d_out, int out_size, void* d_ws, size_t ws_size,
                              hipStream_t stream) {
  const float* feats  = (const float*)d_in[0];
  const float* conv_w = (const float*)d_in[1];
  const float* conv_b = (const float*)d_in[2];
  const float* cbk    = (const float*)d_in[3];
  float* out = (float*)d_out;
  char* ws = (char*)d_ws;
  // workspace layout (bytes), ~31 MB total
  unsigned short* featsT = (unsigned short*)(ws);                  // 16,777,216
  unsigned short* W2     = (unsigned short*)(ws + 16777216);       //    524,288
  unsigned short* cbs    = (unsigned short*)(ws + 17301504);       //  8,388,608
  unsigned short* zb     = (unsigned short*)(ws + 25690112);       //  4,194,304
  int*            cand   = (int*)(ws + 29884416);                  //  1,048,576
  int*            idx    = (int*)(ws + 30932992);                  //     32,768
  float*          lossw  = (float*)(ws + 30965760);                //        256

  k_prep<<<2432, 256, 0, stream>>>(cbk, conv_w, feats, cbs, W2, featsT, lossw);
  k_gemm1<<<dim3(4, 128), 256, 0, stream>>>(featsT, W2, conv_b, zb);
  k_gemm2<<<dim3(32, 128), 256, 0, stream>>>(cbs, zb, cand);
  k_argmin<<<128, 256, 0, stream>>>(zb, cand, idx, lossw, out);
  k_gather<<<256, 256, 0, stream>>>(cbk, idx, out);
}

// Round 4
// 298.681 us; speedup vs baseline: 1.1148x; 1.0697x over previous
//
#include <hip/hip_runtime.h>
#include <hip/hip_bf16.h>
#include <stdint.h>

// Problem: feats[8,1024,32,32]f32, conv_w[256,1024]f32, conv_b[256]f32,
// codebook[16384,256]f32 -> z_q[8,256,32,32]f32 (2097152) + loss scalar.
//
// Round-15 design:
//  - gemm2: r11's PLAIN loop body (no manual rotation buffers - r13/r14 both
//    spilled 300-400 MB scratch) + full ks unroll + launch_bounds(256,3):
//    the compiler picks its own prefetch depth inside a ~170-reg budget.
//    Keeps bias-3.0 acc init + paired v_max3_i32 fold.
//  - argmax: fold encoding is a monotone int -> k_gemm2 atomicMax's directly
//    into best[8192]; cand buffer (8 MB round-trip) and k_argmin kernel die.
//  - k_final = argmin-decode + ||z||^2 + loss + LDS-staged gather (one kernel).
//  - 4 launches instead of 5.

typedef float f32x4 __attribute__((ext_vector_type(4)));
typedef float f32x16 __attribute__((ext_vector_type(16)));
typedef short s16x8 __attribute__((ext_vector_type(8)));

__device__ __forceinline__ void gl2lds16(const void* g, void* l) {
  __builtin_amdgcn_global_load_lds(
      (const __attribute__((address_space(1))) void*)g,
      (__attribute__((address_space(3))) void*)l, 16, 0, 0);
}

__device__ __forceinline__ unsigned short f2bf(float f) {
  unsigned u = __float_as_uint(f);
  u = u + 0x7FFFu + ((u >> 16) & 1u);
  return (unsigned short)(u >> 16);
}
__device__ __forceinline__ float bf2f(unsigned short u) {
  return __uint_as_float(((unsigned)u) << 16);
}

__device__ __forceinline__ ushort4 cvt4(float4 v) {
  ushort4 o;
  o.x = f2bf(v.x); o.y = f2bf(v.y); o.z = f2bf(v.z); o.w = f2bf(v.w);
  return o;
}

// Fused prep, 2432 blocks x 256 thr.
// [0,256):    codebook -> cbs in 32x32x16 A-fragment order. Block jt = 64 j.
//             fl = lp*256+t in [0,2048) maps [ks 16][fr 2][lane 64]:
//             lane holds A[j=jt*64+fr*32+(lane&31)][k=ks*16+(lane>>5)*8 ..+8]
//             blocks 0-7 additionally init best[8192] = INT_MIN.
// [256,384):  conv_w -> W2 bf16, 8 elem/thread
// [384,2432): feats [8][1024 c][1024 s] -> featsT bf16 [8192 i][1024 c]
__global__ void k_prep(const float* __restrict__ cbk, const float* __restrict__ Wsrc,
                       const float* __restrict__ feats,
                       unsigned short* __restrict__ cbs, unsigned short* __restrict__ W2,
                       unsigned short* __restrict__ At, float* __restrict__ lossw,
                       int* __restrict__ best) {
  __shared__ float tile[64][65];
  int blk = blockIdx.x, t = threadIdx.x;
  if (blk == 0 && t < 2) ((int*)lossw)[t] = 0;
  if (blk < 8) {
    #pragma unroll
    for (int k = 0; k < 4; ++k) best[blk * 1024 + k * 256 + t] = (int)0x80000000;
  }
  if (blk < 256) {
    int jt = blk;
    #pragma unroll
    for (int lp = 0; lp < 8; ++lp) {
      int fl = lp * 256 + t;
      int ks = fl >> 7, fr = (fl >> 6) & 1, lane = fl & 63;
      int j = jt * 64 + fr * 32 + (lane & 31);
      int k = ks * 16 + (lane >> 5) * 8;
      const float* src = cbk + (size_t)j * 256 + k;
      float4 v0 = *(const float4*)(src);
      float4 v1 = *(const float4*)(src + 4);
      unsigned short* dst = cbs + ((size_t)jt * 2048 + fl) * 8;
      *(ushort4*)(dst) = cvt4(v0);
      *(ushort4*)(dst + 4) = cvt4(v1);
    }
  } else if (blk < 384) {
    size_t base = (size_t)(blk - 256) * 2048 + t * 8;
    float4 v0 = *(const float4*)(Wsrc + base);
    float4 v1 = *(const float4*)(Wsrc + base + 4);
    *(ushort4*)(W2 + base) = cvt4(v0);
    *(ushort4*)(W2 + base + 4) = cvt4(v1);
  } else {
    int id = blk - 384;
    int b = id >> 8, c0 = ((id >> 4) & 15) * 64, s0 = (id & 15) * 64;
    int tc = t >> 4, ts = (t & 15) * 4;
    #pragma unroll
    for (int k = 0; k < 4; ++k) {
      float4 v = *(const float4*)(feats + ((size_t)b * 1024 + c0 + tc + k * 16) * 1024 + s0 + ts);
      tile[tc + k * 16][ts] = v.x;
      tile[tc + k * 16][ts + 1] = v.y;
      tile[tc + k * 16][ts + 2] = v.z;
      tile[tc + k * 16][ts + 3] = v.w;
    }
    __syncthreads();
    #pragma unroll
    for (int k = 0; k < 4; ++k) {
      int sr = tc + k * 16;
      float4 v;
      v.x = tile[ts][sr]; v.y = tile[ts + 1][sr];
      v.z = tile[ts + 2][sr]; v.w = tile[ts + 3][sr];
      *(ushort4*)(At + (size_t)(b * 1024 + s0 + sr) * 1024 + c0 + ts) = cvt4(v);
    }
  }
}

// GEMM1: z[i][e] = sum_c feats[i][c]*W[e][c] + b[e] (K=1024 bf16) -> zb [i][256].
// BM=BN=64, BK=128 (8 kt iterations, 16 barrier drains), 4 waves 2x2
// (wave 32x32), grid (4,128). LDS 2 x 16 KB.
__global__ __launch_bounds__(256, 2)
void k_gemm1(const unsigned short* __restrict__ At, const unsigned short* __restrict__ Bw,
             const float* __restrict__ bias, unsigned short* __restrict__ zb) {
  __shared__ __align__(16) uint8_t lds[2048 * 16];
  uint8_t* ldsA = lds;
  uint8_t* ldsB = lds + 1024 * 16;
  const int t = threadIdx.x, w = t >> 6, l = t & 63;
  const int wy = w >> 1, wx = w & 1, l15 = l & 15, q = l >> 4;
  const int ib = blockIdx.y * 64, eb = blockIdx.x * 64;
  f32x4 acc[2][2] = {};
  for (int kt = 0; kt < 8; ++kt) {
    int c0 = kt * 128;
    __syncthreads();
    #pragma unroll
    for (int r = 0; r < 4; ++r) {
      int P = t + 256 * r;  // kp = P>>6 (0..15), m = P&63; LDS layout [kp][m]
      gl2lds16(At + (size_t)(ib + (P & 63)) * 1024 + c0 + (P >> 6) * 8, ldsA + P * 16);
    }
    #pragma unroll
    for (int r = 0; r < 4; ++r) {
      int P = t + 256 * r;
      gl2lds16(Bw + (size_t)(eb + (P & 63)) * 1024 + c0 + (P >> 6) * 8, ldsB + P * 16);
    }
    __syncthreads();
    #pragma unroll
    for (int s = 0; s < 4; ++s) {
      s16x8 a[2], b[2];
      #pragma unroll
      for (int fr = 0; fr < 2; ++fr)
        a[fr] = *(const s16x8*)(ldsA + ((s * 4 + q) * 64 + wy * 32 + fr * 16 + l15) * 16);
      #pragma unroll
      for (int fc = 0; fc < 2; ++fc)
        b[fc] = *(const s16x8*)(ldsB + ((s * 4 + q) * 64 + wx * 32 + fc * 16 + l15) * 16);
      #pragma unroll
      for (int fr = 0; fr < 2; ++fr)
        #pragma unroll
        for (int fc = 0; fc < 2; ++fc)
          acc[fr][fc] = __builtin_amdgcn_mfma_f32_16x16x32_bf16(a[fr], b[fc], acc[fr][fc], 0, 0, 0);
    }
  }
  #pragma unroll
  for (int fc = 0; fc < 2; ++fc) {
    int e = eb + wx * 32 + fc * 16 + l15;
    float bv = bias[e];
    #pragma unroll
    for (int fr = 0; fr < 2; ++fr)
      #pragma unroll
      for (int r = 0; r < 4; ++r) {
        int i = ib + wy * 32 + fr * 16 + q * 4 + r;
        zb[(size_t)i * 256 + e] = f2bf(acc[fr][fc][r] + bv);
      }
  }
}

// GEMM2 + argmax, 32x32x16 j-stream. A = cbs (fragment order),
// B = zb [8192 i][256]. 256 thr / 4 waves, i-tile 64 (32 KB LDS, 1 barrier).
// Wave tile 64j x 64i (acc 64 VGPR); wave w streams jtile = bx*8 + js*4 + w.
// grid (32 jsplit, 128 ib), XCD = bx%8 pinned.
// launch_bounds(256,3): ~170-reg budget; PLAIN sequential frag loads + full
// ks unroll -> compiler chooses its own prefetch depth / counted vmcnt
// (manual rotation buffers in r13/r14 both spilled 300-400 MB scratch).
// Bias 3.0 pre-loaded in acc (MFMA C-chain absorbs it).
// Fold: p = (bits(3.0+s)<<14) + (16383-j); paired -> v_max3_i32; block
// result lands via atomicMax into best[8192] (monotone int encoding).
__global__ __launch_bounds__(256, 3)
void k_gemm2(const unsigned short* __restrict__ cbs, const unsigned short* __restrict__ zb,
             int* __restrict__ best) {
  __shared__ __align__(16) uint8_t ldsB[2048 * 16];  // 32 KB: [kp 32][i 64][8 bf16]
  __shared__ int csh[4][64];
  const int t = threadIdx.x, w = t >> 6, l = t & 63;
  const int l31 = l & 31, h = l >> 5;
  const int ib = blockIdx.y * 64;
  // stage zb tile once: packet P -> i = P&63, kp = P>>6
  #pragma unroll
  for (int r = 0; r < 8; ++r) {
    int P = t + 256 * r;
    gl2lds16(zb + (size_t)(ib + (P & 63)) * 256 + (P >> 6) * 8, ldsB + P * 16);
  }
  int rbest[2];
  rbest[0] = rbest[1] = (int)0x80000000;
  __syncthreads();
  const uint8_t* bbase = ldsB + (h * 64 + l31) * 16;  // + ks*2048 + fc*512
  #pragma unroll 1
  for (int js = 0; js < 2; ++js) {
    const int jtile = blockIdx.x * 8 + js * 4 + w;  // 64-j tile index
    const int jw = jtile * 64;
    const uint8_t* abase = (const uint8_t*)cbs + (size_t)jtile * 32768 + l * 16;
    f32x16 acc[2][2];  // [fr j-half][fc i-half], pre-biased at 3.0
    #pragma unroll
    for (int fr = 0; fr < 2; ++fr)
      #pragma unroll
      for (int fc = 0; fc < 2; ++fc)
        #pragma unroll
        for (int rg = 0; rg < 16; ++rg)
          acc[fr][fc][rg] = 3.0f;
    #pragma unroll
    for (int ks = 0; ks < 16; ++ks) {
      s16x8 a0 = *(const s16x8*)(abase + (ks * 2) * 1024);
      s16x8 a1 = *(const s16x8*)(abase + (ks * 2 + 1) * 1024);
      s16x8 b0 = *(const s16x8*)(bbase + ks * 2048);
      s16x8 b1 = *(const s16x8*)(bbase + ks * 2048 + 512);
      acc[0][0] = __builtin_amdgcn_mfma_f32_32x32x16_bf16(a0, b0, acc[0][0], 0, 0, 0);
      acc[0][1] = __builtin_amdgcn_mfma_f32_32x32x16_bf16(a0, b1, acc[0][1], 0, 0, 0);
      acc[1][0] = __builtin_amdgcn_mfma_f32_32x32x16_bf16(a1, b0, acc[1][0], 0, 0, 0);
      acc[1][1] = __builtin_amdgcn_mfma_f32_32x32x16_bf16(a1, b1, acc[1][1], 0, 0, 0);
    }
    // fold: j = jw + fr*32 + (rg&3) + 8*(rg>>2) + 4*h ; i = ib + fc*32 + l31
    const int encb = 16383 - (jw + 4 * h);
    #pragma unroll
    for (int fc = 0; fc < 2; ++fc) {
      int bb = rbest[fc];
      #pragma unroll
      for (int fr = 0; fr < 2; ++fr) {
        const int e1 = encb - fr * 32;
        #pragma unroll
        for (int rg = 0; rg < 16; rg += 2) {
          int e0 = e1 - ((rg & 3) + 8 * (rg >> 2));  // rg even; rg+1 -> e0-1
          int p0 = (int)(((unsigned)__float_as_int(acc[fr][fc][rg]) << 14) + (unsigned)e0);
          int p1 = (int)(((unsigned)__float_as_int(acc[fr][fc][rg + 1]) << 14) + (unsigned)(e0 - 1));
          bb = max(max(p0, p1), bb);  // v_max3_i32
        }
      }
      rbest[fc] = bb;
    }
  }
  // reduce over h (lane>>5 halves hold disjoint j, same i)
  #pragma unroll
  for (int fc = 0; fc < 2; ++fc) {
    int bb = max(rbest[fc], __shfl_xor(rbest[fc], 32, 64));
    if (l < 32) csh[w][fc * 32 + l31] = bb;
  }
  __syncthreads();
  if (t < 64) {
    int m0 = max(max(csh[0][t], csh[1][t]), max(csh[2][t], csh[3][t]));
    atomicMax(&best[ib + t], m0);
  }
}

// Final: decode best -> idx, ||z||^2 + loss, LDS-staged coalesced gather.
// 256 blocks x 256 thr; block = (b, s0) covering 32 rows.
// Loss: dist_i = ||z_i||^2 - (best>>14)*2^-20; block 255 writes the scalar.
// Gather: phase A reads codebook rows as 256B bursts -> tile[32][257];
// phase B writes out[b][e][s0+sl] in 128B contiguous runs (pad 257).
__global__ void k_final(const float* __restrict__ cbk, const unsigned short* __restrict__ zb,
                        const int* __restrict__ best, float* __restrict__ lossw,
                        float* __restrict__ out) {
  __shared__ float tile[32][257];
  __shared__ int lidx[32];
  __shared__ float ps[4];
  int blk = blockIdx.x, t = threadIdx.x;
  int b = blk >> 5, s0 = (blk & 31) * 32;
  int gi0 = b * 1024 + s0;
  int r8 = t >> 3, c8 = t & 7;
  int bv = best[gi0 + r8];  // 8 lanes/addr broadcast
  if (t < 32) lidx[t] = 16383 - (best[gi0 + t] & 0x3FFF);
  // ||z||^2: thread (r8,c8) covers 32 bf16 elems of row gi0+r8
  const unsigned short* zrow = zb + (size_t)(gi0 + r8) * 256 + c8 * 32;
  float ss = 0.0f;
  #pragma unroll
  for (int k = 0; k < 32; k += 4) {
    ushort4 v = *(const ushort4*)(zrow + k);
    float a0 = bf2f(v.x), a1 = bf2f(v.y), a2 = bf2f(v.z), a3 = bf2f(v.w);
    ss += a0 * a0 + a1 * a1 + a2 * a2 + a3 * a3;
  }
  ss += __shfl_xor(ss, 1, 64);
  ss += __shfl_xor(ss, 2, 64);
  ss += __shfl_xor(ss, 4, 64);
  float dist = 0.0f;
  if (c8 == 0) dist = ss - (float)(bv >> 14) * (1.0f / 1048576.0f);  // 2*score
  float v = dist;
  #pragma unroll
  for (int m = 32; m; m >>= 1) v += __shfl_down(v, m, 64);
  if ((t & 63) == 0) ps[t >> 6] = v;
  __syncthreads();
  if (t == 0) {
    float part = ps[0] + ps[1] + ps[2] + ps[3];
    atomicAdd(lossw, part);
    __threadfence();
    int cnt = atomicAdd((int*)lossw + 1, 1);
    if (cnt == 255) {
      __threadfence();
      float total = atomicAdd(lossw, 0.0f);
      out[2097152] = 1.25f * total * (1.0f / 2097152.0f);
    }
  }
  // gather (lidx is barrier-protected by the __syncthreads above)
  int w = t >> 6, l = t & 63;
  #pragma unroll
  for (int rr = 0; rr < 8; ++rr) {
    int r = w * 8 + rr;
    const float* src = cbk + (size_t)lidx[r] * 256;
    #pragma unroll
    for (int k = 0; k < 4; ++k)
      tile[r][l + 64 * k] = src[l + 64 * k];
  }
  __syncthreads();
  int sl = t & 31, eg = t >> 5;  // eg 0..7
  size_t ob = (size_t)b * 262144 + s0 + sl;
  #pragma unroll
  for (int k = 0; k < 32; ++k) {
    int e = eg + 8 * k;
    out[ob + (size_t)e * 1024] = tile[sl][e];
  }
}

extern "C" void kernel_launch(void* const* d_in, const int* in_sizes, int n_in,
                              void* d_out, int out_size, void* d_ws, size_t ws_size,
                              hipStream_t stream) {
  const float* feats  = (const float*)d_in[0];
  const float* conv_w = (const float*)d_in[1];
  const float* conv_b = (const float*)d_in[2];
  const float* cbk    = (const float*)d_in[3];
  float* out = (float*)d_out;
  char* ws = (char*)d_ws;
  // workspace layout (bytes), ~30 MB total
  unsigned short* featsT = (unsigned short*)(ws);                  // 16,777,216
  unsigned short* W2     = (unsigned short*)(ws + 16777216);       //    524,288
  unsigned short* cbs    = (unsigned short*)(ws + 17301504);       //  8,388,608
  unsigned short* zb     = (unsigned short*)(ws + 25690112);       //  4,194,304
  int*            best   = (int*)(ws + 29884416);                  //     32,768
  float*          lossw  = (float*)(ws + 29917184);                //        256

  k_prep<<<2432, 256, 0, stream>>>(cbk, conv_w, feats, cbs, W2, featsT, lossw, best);
  k_gemm1<<<dim3(4, 128), 256, 0, stream>>>(featsT, W2, conv_b, zb);
  k_gemm2<<<dim3(32, 128), 256, 0, stream>>>(cbs, zb, best);
  k_final<<<256, 256, 0, stream>>>(cbk, zb, best, lossw, out);
}

// Round 5
// 195.531 us; speedup vs baseline: 1.7029x; 1.5275x over previous
//
#include <hip/hip_runtime.h>
#include <hip/hip_bf16.h>
#include <stdint.h>

// Problem: feats[8,1024,32,32]f32, conv_w[256,1024]f32, conv_b[256]f32,
// codebook[16384,256]f32 -> z_q[8,256,32,32]f32 (2097152) + loss scalar.
//
// Round-16 design:
//  - gemm2: wave tile 64j x 128i (acc 128 AGPR), launch_bounds(256,2) for a
//    256-reg budget. Same 2 global A-loads per ks now feed 8 MFMAs (64 cy),
//    so A-latency needs only ~2x coverage (unroll 2 + 2 waves/SIMD) instead
//    of the depth-4+ register pipeline that spilled in r13/r14/r15.
//    UNROLL DISCIPLINE: ks loop at #pragma unroll 2 — the compiler pipelines
//    to the unroll window; wider windows (r15 full unroll) hoist 32 load
//    dests and spill acc (308-420 MB scratch).
//    Keeps bias-3.0 acc init + paired v_max3_i32 fold + atomicMax output.
//  - 4 launches: prep, gemm1, gemm2, final.

typedef float f32x4 __attribute__((ext_vector_type(4)));
typedef float f32x16 __attribute__((ext_vector_type(16)));
typedef short s16x8 __attribute__((ext_vector_type(8)));

__device__ __forceinline__ void gl2lds16(const void* g, void* l) {
  __builtin_amdgcn_global_load_lds(
      (const __attribute__((address_space(1))) void*)g,
      (__attribute__((address_space(3))) void*)l, 16, 0, 0);
}

__device__ __forceinline__ unsigned short f2bf(float f) {
  unsigned u = __float_as_uint(f);
  u = u + 0x7FFFu + ((u >> 16) & 1u);
  return (unsigned short)(u >> 16);
}
__device__ __forceinline__ float bf2f(unsigned short u) {
  return __uint_as_float(((unsigned)u) << 16);
}

__device__ __forceinline__ ushort4 cvt4(float4 v) {
  ushort4 o;
  o.x = f2bf(v.x); o.y = f2bf(v.y); o.z = f2bf(v.z); o.w = f2bf(v.w);
  return o;
}

// Fused prep, 2432 blocks x 256 thr.
// [0,256):    codebook -> cbs in 32x32x16 A-fragment order. Block jt = 64 j.
//             fl = lp*256+t in [0,2048) maps [ks 16][fr 2][lane 64]:
//             lane holds A[j=jt*64+fr*32+(lane&31)][k=ks*16+(lane>>5)*8 ..+8]
//             blocks 0-7 additionally init best[8192] = INT_MIN.
// [256,384):  conv_w -> W2 bf16, 8 elem/thread
// [384,2432): feats [8][1024 c][1024 s] -> featsT bf16 [8192 i][1024 c]
__global__ void k_prep(const float* __restrict__ cbk, const float* __restrict__ Wsrc,
                       const float* __restrict__ feats,
                       unsigned short* __restrict__ cbs, unsigned short* __restrict__ W2,
                       unsigned short* __restrict__ At, float* __restrict__ lossw,
                       int* __restrict__ best) {
  __shared__ float tile[64][65];
  int blk = blockIdx.x, t = threadIdx.x;
  if (blk == 0 && t < 2) ((int*)lossw)[t] = 0;
  if (blk < 8) {
    #pragma unroll
    for (int k = 0; k < 4; ++k) best[blk * 1024 + k * 256 + t] = (int)0x80000000;
  }
  if (blk < 256) {
    int jt = blk;
    #pragma unroll
    for (int lp = 0; lp < 8; ++lp) {
      int fl = lp * 256 + t;
      int ks = fl >> 7, fr = (fl >> 6) & 1, lane = fl & 63;
      int j = jt * 64 + fr * 32 + (lane & 31);
      int k = ks * 16 + (lane >> 5) * 8;
      const float* src = cbk + (size_t)j * 256 + k;
      float4 v0 = *(const float4*)(src);
      float4 v1 = *(const float4*)(src + 4);
      unsigned short* dst = cbs + ((size_t)jt * 2048 + fl) * 8;
      *(ushort4*)(dst) = cvt4(v0);
      *(ushort4*)(dst + 4) = cvt4(v1);
    }
  } else if (blk < 384) {
    size_t base = (size_t)(blk - 256) * 2048 + t * 8;
    float4 v0 = *(const float4*)(Wsrc + base);
    float4 v1 = *(const float4*)(Wsrc + base + 4);
    *(ushort4*)(W2 + base) = cvt4(v0);
    *(ushort4*)(W2 + base + 4) = cvt4(v1);
  } else {
    int id = blk - 384;
    int b = id >> 8, c0 = ((id >> 4) & 15) * 64, s0 = (id & 15) * 64;
    int tc = t >> 4, ts = (t & 15) * 4;
    #pragma unroll
    for (int k = 0; k < 4; ++k) {
      float4 v = *(const float4*)(feats + ((size_t)b * 1024 + c0 + tc + k * 16) * 1024 + s0 + ts);
      tile[tc + k * 16][ts] = v.x;
      tile[tc + k * 16][ts + 1] = v.y;
      tile[tc + k * 16][ts + 2] = v.z;
      tile[tc + k * 16][ts + 3] = v.w;
    }
    __syncthreads();
    #pragma unroll
    for (int k = 0; k < 4; ++k) {
      int sr = tc + k * 16;
      float4 v;
      v.x = tile[ts][sr]; v.y = tile[ts + 1][sr];
      v.z = tile[ts + 2][sr]; v.w = tile[ts + 3][sr];
      *(ushort4*)(At + (size_t)(b * 1024 + s0 + sr) * 1024 + c0 + ts) = cvt4(v);
    }
  }
}

// GEMM1: z[i][e] = sum_c feats[i][c]*W[e][c] + b[e] (K=1024 bf16) -> zb [i][256].
// BM=BN=64, BK=128 (8 kt iterations, 16 barrier drains), 4 waves 2x2
// (wave 32x32), grid (4,128). LDS 2 x 16 KB.
__global__ __launch_bounds__(256, 2)
void k_gemm1(const unsigned short* __restrict__ At, const unsigned short* __restrict__ Bw,
             const float* __restrict__ bias, unsigned short* __restrict__ zb) {
  __shared__ __align__(16) uint8_t lds[2048 * 16];
  uint8_t* ldsA = lds;
  uint8_t* ldsB = lds + 1024 * 16;
  const int t = threadIdx.x, w = t >> 6, l = t & 63;
  const int wy = w >> 1, wx = w & 1, l15 = l & 15, q = l >> 4;
  const int ib = blockIdx.y * 64, eb = blockIdx.x * 64;
  f32x4 acc[2][2] = {};
  for (int kt = 0; kt < 8; ++kt) {
    int c0 = kt * 128;
    __syncthreads();
    #pragma unroll
    for (int r = 0; r < 4; ++r) {
      int P = t + 256 * r;  // kp = P>>6 (0..15), m = P&63; LDS layout [kp][m]
      gl2lds16(At + (size_t)(ib + (P & 63)) * 1024 + c0 + (P >> 6) * 8, ldsA + P * 16);
    }
    #pragma unroll
    for (int r = 0; r < 4; ++r) {
      int P = t + 256 * r;
      gl2lds16(Bw + (size_t)(eb + (P & 63)) * 1024 + c0 + (P >> 6) * 8, ldsB + P * 16);
    }
    __syncthreads();
    #pragma unroll
    for (int s = 0; s < 4; ++s) {
      s16x8 a[2], b[2];
      #pragma unroll
      for (int fr = 0; fr < 2; ++fr)
        a[fr] = *(const s16x8*)(ldsA + ((s * 4 + q) * 64 + wy * 32 + fr * 16 + l15) * 16);
      #pragma unroll
      for (int fc = 0; fc < 2; ++fc)
        b[fc] = *(const s16x8*)(ldsB + ((s * 4 + q) * 64 + wx * 32 + fc * 16 + l15) * 16);
      #pragma unroll
      for (int fr = 0; fr < 2; ++fr)
        #pragma unroll
        for (int fc = 0; fc < 2; ++fc)
          acc[fr][fc] = __builtin_amdgcn_mfma_f32_16x16x32_bf16(a[fr], b[fc], acc[fr][fc], 0, 0, 0);
    }
  }
  #pragma unroll
  for (int fc = 0; fc < 2; ++fc) {
    int e = eb + wx * 32 + fc * 16 + l15;
    float bv = bias[e];
    #pragma unroll
    for (int fr = 0; fr < 2; ++fr)
      #pragma unroll
      for (int r = 0; r < 4; ++r) {
        int i = ib + wy * 32 + fr * 16 + q * 4 + r;
        zb[(size_t)i * 256 + e] = f2bf(acc[fr][fc][r] + bv);
      }
  }
}

// GEMM2 + argmax, 32x32x16 j-stream. A = cbs (fragment order),
// B = zb [8192 i][256]. 256 thr / 4 waves, i-tile 128 (64 KB LDS, 1 barrier).
// Wave tile 64j x 128i: acc[2][4] = 128 AGPR; per ks the wave's 2 global
// A-loads feed 8 MFMAs (64 cy), so latency coverage needs only the unroll-2
// window + the 2nd wave/SIMD. launch_bounds(256,2) -> 256-reg budget
// (128 AGPR acc + ~90 VGPR, no cap pressure, no spill).
// Wave w streams jtile = bx*8 + js*4 + w; grid (32 jsplit, 64 ib),
// XCD = bx%8 pinned. L2 A-traffic halves vs i-tile-64 (537 MB).
// Bias 3.0 pre-loaded in acc (MFMA C-chain absorbs it).
// Fold: p = (bits(3.0+s)<<14) + (16383-j); paired -> v_max3_i32;
// atomicMax into best[8192] (monotone int encoding).
__global__ __launch_bounds__(256, 2)
void k_gemm2(const unsigned short* __restrict__ cbs, const unsigned short* __restrict__ zb,
             int* __restrict__ best) {
  __shared__ __align__(16) uint8_t ldsB[65536];  // 64 KB: [kp 32][i 128][8 bf16]
  __shared__ int csh[4][128];
  const int t = threadIdx.x, w = t >> 6, l = t & 63;
  const int l31 = l & 31, h = l >> 5;
  const int ib = blockIdx.y * 128;
  // stage zb tile once: packet P -> i = P&127, kp = P>>7
  #pragma unroll
  for (int r = 0; r < 16; ++r) {
    int P = t + 256 * r;
    gl2lds16(zb + (size_t)(ib + (P & 127)) * 256 + (P >> 7) * 8, ldsB + P * 16);
  }
  int rbest[4];
  #pragma unroll
  for (int fc = 0; fc < 4; ++fc) rbest[fc] = (int)0x80000000;
  __syncthreads();
  const uint8_t* bbase = ldsB + (h * 128 + l31) * 16;  // + ks*4096 + fc*512
  #pragma unroll 1
  for (int js = 0; js < 2; ++js) {
    const int jtile = blockIdx.x * 8 + js * 4 + w;  // 64-j tile index
    const int jw = jtile * 64;
    const uint8_t* abase = (const uint8_t*)cbs + (size_t)jtile * 32768 + l * 16;
    f32x16 acc[2][4];  // [fr j-half][fc i-quarter], pre-biased at 3.0
    #pragma unroll
    for (int fr = 0; fr < 2; ++fr)
      #pragma unroll
      for (int fc = 0; fc < 4; ++fc)
        #pragma unroll
        for (int rg = 0; rg < 16; ++rg)
          acc[fr][fc][rg] = 3.0f;
    #pragma unroll 2
    for (int ks = 0; ks < 16; ++ks) {
      s16x8 a0 = *(const s16x8*)(abase + (ks * 2) * 1024);
      s16x8 a1 = *(const s16x8*)(abase + (ks * 2 + 1) * 1024);
      s16x8 b0 = *(const s16x8*)(bbase + ks * 4096);
      s16x8 b1 = *(const s16x8*)(bbase + ks * 4096 + 512);
      s16x8 b2 = *(const s16x8*)(bbase + ks * 4096 + 1024);
      s16x8 b3 = *(const s16x8*)(bbase + ks * 4096 + 1536);
      acc[0][0] = __builtin_amdgcn_mfma_f32_32x32x16_bf16(a0, b0, acc[0][0], 0, 0, 0);
      acc[1][0] = __builtin_amdgcn_mfma_f32_32x32x16_bf16(a1, b0, acc[1][0], 0, 0, 0);
      acc[0][1] = __builtin_amdgcn_mfma_f32_32x32x16_bf16(a0, b1, acc[0][1], 0, 0, 0);
      acc[1][1] = __builtin_amdgcn_mfma_f32_32x32x16_bf16(a1, b1, acc[1][1], 0, 0, 0);
      acc[0][2] = __builtin_amdgcn_mfma_f32_32x32x16_bf16(a0, b2, acc[0][2], 0, 0, 0);
      acc[1][2] = __builtin_amdgcn_mfma_f32_32x32x16_bf16(a1, b2, acc[1][2], 0, 0, 0);
      acc[0][3] = __builtin_amdgcn_mfma_f32_32x32x16_bf16(a0, b3, acc[0][3], 0, 0, 0);
      acc[1][3] = __builtin_amdgcn_mfma_f32_32x32x16_bf16(a1, b3, acc[1][3], 0, 0, 0);
    }
    // fold: j = jw + fr*32 + (rg&3) + 8*(rg>>2) + 4*h ; i = ib + fc*32 + l31
    const int encb = 16383 - (jw + 4 * h);
    #pragma unroll
    for (int fc = 0; fc < 4; ++fc) {
      int bb = rbest[fc];
      #pragma unroll
      for (int fr = 0; fr < 2; ++fr) {
        const int e1 = encb - fr * 32;
        #pragma unroll
        for (int rg = 0; rg < 16; rg += 2) {
          int e0 = e1 - ((rg & 3) + 8 * (rg >> 2));  // rg even; rg+1 -> e0-1
          int p0 = (int)(((unsigned)__float_as_int(acc[fr][fc][rg]) << 14) + (unsigned)e0);
          int p1 = (int)(((unsigned)__float_as_int(acc[fr][fc][rg + 1]) << 14) + (unsigned)(e0 - 1));
          bb = max(max(p0, p1), bb);  // v_max3_i32
        }
      }
      rbest[fc] = bb;
    }
  }
  // reduce over h (lane>>5 halves hold disjoint j, same i)
  #pragma unroll
  for (int fc = 0; fc < 4; ++fc) {
    int bb = max(rbest[fc], __shfl_xor(rbest[fc], 32, 64));
    if (l < 32) csh[w][fc * 32 + l31] = bb;
  }
  __syncthreads();
  if (t < 128) {
    int m0 = max(max(csh[0][t], csh[1][t]), max(csh[2][t], csh[3][t]));
    atomicMax(&best[ib + t], m0);
  }
}

// Final: decode best -> idx, ||z||^2 + loss, LDS-staged coalesced gather.
// 256 blocks x 256 thr; block = (b, s0) covering 32 rows.
// Loss: dist_i = ||z_i||^2 - (best>>14)*2^-20; last block writes the scalar.
// Gather: phase A reads codebook rows as 256B bursts -> tile[32][257];
// phase B writes out[b][e][s0+sl] in 128B contiguous runs (pad 257).
__global__ void k_final(const float* __restrict__ cbk, const unsigned short* __restrict__ zb,
                        const int* __restrict__ best, float* __restrict__ lossw,
                        float* __restrict__ out) {
  __shared__ float tile[32][257];
  __shared__ int lidx[32];
  __shared__ float ps[4];
  int blk = blockIdx.x, t = threadIdx.x;
  int b = blk >> 5, s0 = (blk & 31) * 32;
  int gi0 = b * 1024 + s0;
  int r8 = t >> 3, c8 = t & 7;
  int bv = best[gi0 + r8];  // 8 lanes/addr broadcast
  if (t < 32) lidx[t] = 16383 - (best[gi0 + t] & 0x3FFF);
  // ||z||^2: thread (r8,c8) covers 32 bf16 elems of row gi0+r8
  const unsigned short* zrow = zb + (size_t)(gi0 + r8) * 256 + c8 * 32;
  float ss = 0.0f;
  #pragma unroll
  for (int k = 0; k < 32; k += 4) {
    ushort4 v = *(const ushort4*)(zrow + k);
    float a0 = bf2f(v.x), a1 = bf2f(v.y), a2 = bf2f(v.z), a3 = bf2f(v.w);
    ss += a0 * a0 + a1 * a1 + a2 * a2 + a3 * a3;
  }
  ss += __shfl_xor(ss, 1, 64);
  ss += __shfl_xor(ss, 2, 64);
  ss += __shfl_xor(ss, 4, 64);
  float dist = 0.0f;
  if (c8 == 0) dist = ss - (float)(bv >> 14) * (1.0f / 1048576.0f);  // 2*score
  float v = dist;
  #pragma unroll
  for (int m = 32; m; m >>= 1) v += __shfl_down(v, m, 64);
  if ((t & 63) == 0) ps[t >> 6] = v;
  __syncthreads();
  if (t == 0) {
    float part = ps[0] + ps[1] + ps[2] + ps[3];
    atomicAdd(lossw, part);
    __threadfence();
    int cnt = atomicAdd((int*)lossw + 1, 1);
    if (cnt == 255) {
      __threadfence();
      float total = atomicAdd(lossw, 0.0f);
      out[2097152] = 1.25f * total * (1.0f / 2097152.0f);
    }
  }
  // gather (lidx is barrier-protected by the __syncthreads above)
  int w = t >> 6, l = t & 63;
  #pragma unroll
  for (int rr = 0; rr < 8; ++rr) {
    int r = w * 8 + rr;
    const float* src = cbk + (size_t)lidx[r] * 256;
    #pragma unroll
    for (int k = 0; k < 4; ++k)
      tile[r][l + 64 * k] = src[l + 64 * k];
  }
  __syncthreads();
  int sl = t & 31, eg = t >> 5;  // eg 0..7
  size_t ob = (size_t)b * 262144 + s0 + sl;
  #pragma unroll
  for (int k = 0; k < 32; ++k) {
    int e = eg + 8 * k;
    out[ob + (size_t)e * 1024] = tile[sl][e];
  }
}

extern "C" void kernel_launch(void* const* d_in, const int* in_sizes, int n_in,
                              void* d_out, int out_size, void* d_ws, size_t ws_size,
                              hipStream_t stream) {
  const float* feats  = (const float*)d_in[0];
  const float* conv_w = (const float*)d_in[1];
  const float* conv_b = (const float*)d_in[2];
  const float* cbk    = (const float*)d_in[3];
  float* out = (float*)d_out;
  char* ws = (char*)d_ws;
  // workspace layout (bytes), ~30 MB total
  unsigned short* featsT = (unsigned short*)(ws);                  // 16,777,216
  unsigned short* W2     = (unsigned short*)(ws + 16777216);       //    524,288
  unsigned short* cbs    = (unsigned short*)(ws + 17301504);       //  8,388,608
  unsigned short* zb     = (unsigned short*)(ws + 25690112);       //  4,194,304
  int*            best   = (int*)(ws + 29884416);                  //     32,768
  float*          lossw  = (float*)(ws + 29917184);                //        256

  k_prep<<<2432, 256, 0, stream>>>(cbk, conv_w, feats, cbs, W2, featsT, lossw, best);
  k_gemm1<<<dim3(4, 128), 256, 0, stream>>>(featsT, W2, conv_b, zb);
  k_gemm2<<<dim3(32, 64), 256, 0, stream>>>(cbs, zb, best);
  k_final<<<256, 256, 0, stream>>>(cbk, zb, best, lossw, out);
}

// Round 6
// 194.708 us; speedup vs baseline: 1.7101x; 1.0042x over previous
//
#include <hip/hip_runtime.h>
#include <hip/hip_bf16.h>
#include <stdint.h>

// Problem: feats[8,1024,32,32]f32, conv_w[256,1024]f32, conv_b[256]f32,
// codebook[16384,256]f32 -> z_q[8,256,32,32]f32 (2097152) + loss scalar.
//
// Round-17 design:
//  - gemm2: r16 geometry exactly (64j x 128i wave tile, acc 128 AGPR,
//    launch_bounds(256,2), unroll 2, no manual buffers - no spill at VGPR 88)
//    + WAVE PHASE STAGGER: each wave starts its ks sweep at a different
//    rotation ((w+bx+by)&3)*4. r11/r12/r16 all measured MfmaUtil ~= the
//    single-wave duty cycle (35-38%) regardless of geometry => co-resident
//    waves run lockstep cadence and stall on L2 A-loads in phase. Rotating
//    the K start desynchronizes them so one wave's MFMA cluster covers the
//    other's load stall. K-sum is order-independent (fp reorder only).
//  - 4 launches: prep, gemm1, gemm2, final.

typedef float f32x4 __attribute__((ext_vector_type(4)));
typedef float f32x16 __attribute__((ext_vector_type(16)));
typedef short s16x8 __attribute__((ext_vector_type(8)));

__device__ __forceinline__ void gl2lds16(const void* g, void* l) {
  __builtin_amdgcn_global_load_lds(
      (const __attribute__((address_space(1))) void*)g,
      (__attribute__((address_space(3))) void*)l, 16, 0, 0);
}

__device__ __forceinline__ unsigned short f2bf(float f) {
  unsigned u = __float_as_uint(f);
  u = u + 0x7FFFu + ((u >> 16) & 1u);
  return (unsigned short)(u >> 16);
}
__device__ __forceinline__ float bf2f(unsigned short u) {
  return __uint_as_float(((unsigned)u) << 16);
}

__device__ __forceinline__ ushort4 cvt4(float4 v) {
  ushort4 o;
  o.x = f2bf(v.x); o.y = f2bf(v.y); o.z = f2bf(v.z); o.w = f2bf(v.w);
  return o;
}

// Fused prep, 2432 blocks x 256 thr.
// [0,256):    codebook -> cbs in 32x32x16 A-fragment order. Block jt = 64 j.
//             fl = lp*256+t in [0,2048) maps [ks 16][fr 2][lane 64]:
//             lane holds A[j=jt*64+fr*32+(lane&31)][k=ks*16+(lane>>5)*8 ..+8]
//             blocks 0-7 additionally init best[8192] = INT_MIN.
// [256,384):  conv_w -> W2 bf16, 8 elem/thread
// [384,2432): feats [8][1024 c][1024 s] -> featsT bf16 [8192 i][1024 c]
__global__ void k_prep(const float* __restrict__ cbk, const float* __restrict__ Wsrc,
                       const float* __restrict__ feats,
                       unsigned short* __restrict__ cbs, unsigned short* __restrict__ W2,
                       unsigned short* __restrict__ At, float* __restrict__ lossw,
                       int* __restrict__ best) {
  __shared__ float tile[64][65];
  int blk = blockIdx.x, t = threadIdx.x;
  if (blk == 0 && t < 2) ((int*)lossw)[t] = 0;
  if (blk < 8) {
    #pragma unroll
    for (int k = 0; k < 4; ++k) best[blk * 1024 + k * 256 + t] = (int)0x80000000;
  }
  if (blk < 256) {
    int jt = blk;
    #pragma unroll
    for (int lp = 0; lp < 8; ++lp) {
      int fl = lp * 256 + t;
      int ks = fl >> 7, fr = (fl >> 6) & 1, lane = fl & 63;
      int j = jt * 64 + fr * 32 + (lane & 31);
      int k = ks * 16 + (lane >> 5) * 8;
      const float* src = cbk + (size_t)j * 256 + k;
      float4 v0 = *(const float4*)(src);
      float4 v1 = *(const float4*)(src + 4);
      unsigned short* dst = cbs + ((size_t)jt * 2048 + fl) * 8;
      *(ushort4*)(dst) = cvt4(v0);
      *(ushort4*)(dst + 4) = cvt4(v1);
    }
  } else if (blk < 384) {
    size_t base = (size_t)(blk - 256) * 2048 + t * 8;
    float4 v0 = *(const float4*)(Wsrc + base);
    float4 v1 = *(const float4*)(Wsrc + base + 4);
    *(ushort4*)(W2 + base) = cvt4(v0);
    *(ushort4*)(W2 + base + 4) = cvt4(v1);
  } else {
    int id = blk - 384;
    int b = id >> 8, c0 = ((id >> 4) & 15) * 64, s0 = (id & 15) * 64;
    int tc = t >> 4, ts = (t & 15) * 4;
    #pragma unroll
    for (int k = 0; k < 4; ++k) {
      float4 v = *(const float4*)(feats + ((size_t)b * 1024 + c0 + tc + k * 16) * 1024 + s0 + ts);
      tile[tc + k * 16][ts] = v.x;
      tile[tc + k * 16][ts + 1] = v.y;
      tile[tc + k * 16][ts + 2] = v.z;
      tile[tc + k * 16][ts + 3] = v.w;
    }
    __syncthreads();
    #pragma unroll
    for (int k = 0; k < 4; ++k) {
      int sr = tc + k * 16;
      float4 v;
      v.x = tile[ts][sr]; v.y = tile[ts + 1][sr];
      v.z = tile[ts + 2][sr]; v.w = tile[ts + 3][sr];
      *(ushort4*)(At + (size_t)(b * 1024 + s0 + sr) * 1024 + c0 + ts) = cvt4(v);
    }
  }
}

// GEMM1: z[i][e] = sum_c feats[i][c]*W[e][c] + b[e] (K=1024 bf16) -> zb [i][256].
// BM=BN=64, BK=128 (8 kt iterations, 16 barrier drains), 4 waves 2x2
// (wave 32x32), grid (4,128). LDS 2 x 16 KB.
__global__ __launch_bounds__(256, 2)
void k_gemm1(const unsigned short* __restrict__ At, const unsigned short* __restrict__ Bw,
             const float* __restrict__ bias, unsigned short* __restrict__ zb) {
  __shared__ __align__(16) uint8_t lds[2048 * 16];
  uint8_t* ldsA = lds;
  uint8_t* ldsB = lds + 1024 * 16;
  const int t = threadIdx.x, w = t >> 6, l = t & 63;
  const int wy = w >> 1, wx = w & 1, l15 = l & 15, q = l >> 4;
  const int ib = blockIdx.y * 64, eb = blockIdx.x * 64;
  f32x4 acc[2][2] = {};
  for (int kt = 0; kt < 8; ++kt) {
    int c0 = kt * 128;
    __syncthreads();
    #pragma unroll
    for (int r = 0; r < 4; ++r) {
      int P = t + 256 * r;  // kp = P>>6 (0..15), m = P&63; LDS layout [kp][m]
      gl2lds16(At + (size_t)(ib + (P & 63)) * 1024 + c0 + (P >> 6) * 8, ldsA + P * 16);
    }
    #pragma unroll
    for (int r = 0; r < 4; ++r) {
      int P = t + 256 * r;
      gl2lds16(Bw + (size_t)(eb + (P & 63)) * 1024 + c0 + (P >> 6) * 8, ldsB + P * 16);
    }
    __syncthreads();
    #pragma unroll
    for (int s = 0; s < 4; ++s) {
      s16x8 a[2], b[2];
      #pragma unroll
      for (int fr = 0; fr < 2; ++fr)
        a[fr] = *(const s16x8*)(ldsA + ((s * 4 + q) * 64 + wy * 32 + fr * 16 + l15) * 16);
      #pragma unroll
      for (int fc = 0; fc < 2; ++fc)
        b[fc] = *(const s16x8*)(ldsB + ((s * 4 + q) * 64 + wx * 32 + fc * 16 + l15) * 16);
      #pragma unroll
      for (int fr = 0; fr < 2; ++fr)
        #pragma unroll
        for (int fc = 0; fc < 2; ++fc)
          acc[fr][fc] = __builtin_amdgcn_mfma_f32_16x16x32_bf16(a[fr], b[fc], acc[fr][fc], 0, 0, 0);
    }
  }
  #pragma unroll
  for (int fc = 0; fc < 2; ++fc) {
    int e = eb + wx * 32 + fc * 16 + l15;
    float bv = bias[e];
    #pragma unroll
    for (int fr = 0; fr < 2; ++fr)
      #pragma unroll
      for (int r = 0; r < 4; ++r) {
        int i = ib + wy * 32 + fr * 16 + q * 4 + r;
        zb[(size_t)i * 256 + e] = f2bf(acc[fr][fc][r] + bv);
      }
  }
}

// GEMM2 + argmax, 32x32x16 j-stream. A = cbs (fragment order),
// B = zb [8192 i][256]. 256 thr / 4 waves, i-tile 128 (64 KB LDS, 1 barrier).
// Wave tile 64j x 128i: acc[2][4] = 128 AGPR, launch_bounds(256,2), unroll 2
// (r16 config, no spill at VGPR 88).
// WAVE PHASE STAGGER: ks sweep starts at rotation ((w+bx+by)&3)*4 per wave,
// so co-resident waves' L2-load stalls and MFMA clusters interleave instead
// of colliding in lockstep (r11/r12/r16 all pinned at single-wave duty
// ~35-38% regardless of geometry). K-sum is order-independent.
// Wave w streams jtile = bx*8 + js*4 + w; grid (32 jsplit, 64 ib),
// XCD = bx%8 pinned.
// Bias 3.0 pre-loaded in acc (MFMA C-chain absorbs it).
// Fold: p = (bits(3.0+s)<<14) + (16383-j); paired -> v_max3_i32;
// atomicMax into best[8192] (monotone int encoding).
__global__ __launch_bounds__(256, 2)
void k_gemm2(const unsigned short* __restrict__ cbs, const unsigned short* __restrict__ zb,
             int* __restrict__ best) {
  __shared__ __align__(16) uint8_t ldsB[65536];  // 64 KB: [kp 32][i 128][8 bf16]
  __shared__ int csh[4][128];
  const int t = threadIdx.x, w = t >> 6, l = t & 63;
  const int l31 = l & 31, h = l >> 5;
  const int ib = blockIdx.y * 128;
  // stage zb tile once: packet P -> i = P&127, kp = P>>7
  #pragma unroll
  for (int r = 0; r < 16; ++r) {
    int P = t + 256 * r;
    gl2lds16(zb + (size_t)(ib + (P & 127)) * 256 + (P >> 7) * 8, ldsB + P * 16);
  }
  int rbest[4];
  #pragma unroll
  for (int fc = 0; fc < 4; ++fc) rbest[fc] = (int)0x80000000;
  const int koff = ((w + blockIdx.x + blockIdx.y) & 3) * 4;  // wave phase stagger
  __syncthreads();
  const uint8_t* bbase = ldsB + (h * 128 + l31) * 16;  // + ks*4096 + fc*512
  #pragma unroll 1
  for (int js = 0; js < 2; ++js) {
    const int jtile = blockIdx.x * 8 + js * 4 + w;  // 64-j tile index
    const int jw = jtile * 64;
    const uint8_t* abase = (const uint8_t*)cbs + (size_t)jtile * 32768 + l * 16;
    f32x16 acc[2][4];  // [fr j-half][fc i-quarter], pre-biased at 3.0
    #pragma unroll
    for (int fr = 0; fr < 2; ++fr)
      #pragma unroll
      for (int fc = 0; fc < 4; ++fc)
        #pragma unroll
        for (int rg = 0; rg < 16; ++rg)
          acc[fr][fc][rg] = 3.0f;
    #pragma unroll 2
    for (int ks0 = 0; ks0 < 16; ++ks0) {
      const int ks = (ks0 + koff) & 15;
      s16x8 a0 = *(const s16x8*)(abase + (ks * 2) * 1024);
      s16x8 a1 = *(const s16x8*)(abase + (ks * 2 + 1) * 1024);
      s16x8 b0 = *(const s16x8*)(bbase + ks * 4096);
      s16x8 b1 = *(const s16x8*)(bbase + ks * 4096 + 512);
      s16x8 b2 = *(const s16x8*)(bbase + ks * 4096 + 1024);
      s16x8 b3 = *(const s16x8*)(bbase + ks * 4096 + 1536);
      acc[0][0] = __builtin_amdgcn_mfma_f32_32x32x16_bf16(a0, b0, acc[0][0], 0, 0, 0);
      acc[1][0] = __builtin_amdgcn_mfma_f32_32x32x16_bf16(a1, b0, acc[1][0], 0, 0, 0);
      acc[0][1] = __builtin_amdgcn_mfma_f32_32x32x16_bf16(a0, b1, acc[0][1], 0, 0, 0);
      acc[1][1] = __builtin_amdgcn_mfma_f32_32x32x16_bf16(a1, b1, acc[1][1], 0, 0, 0);
      acc[0][2] = __builtin_amdgcn_mfma_f32_32x32x16_bf16(a0, b2, acc[0][2], 0, 0, 0);
      acc[1][2] = __builtin_amdgcn_mfma_f32_32x32x16_bf16(a1, b2, acc[1][2], 0, 0, 0);
      acc[0][3] = __builtin_amdgcn_mfma_f32_32x32x16_bf16(a0, b3, acc[0][3], 0, 0, 0);
      acc[1][3] = __builtin_amdgcn_mfma_f32_32x32x16_bf16(a1, b3, acc[1][3], 0, 0, 0);
    }
    // fold: j = jw + fr*32 + (rg&3) + 8*(rg>>2) + 4*h ; i = ib + fc*32 + l31
    const int encb = 16383 - (jw + 4 * h);
    #pragma unroll
    for (int fc = 0; fc < 4; ++fc) {
      int bb = rbest[fc];
      #pragma unroll
      for (int fr = 0; fr < 2; ++fr) {
        const int e1 = encb - fr * 32;
        #pragma unroll
        for (int rg = 0; rg < 16; rg += 2) {
          int e0 = e1 - ((rg & 3) + 8 * (rg >> 2));  // rg even; rg+1 -> e0-1
          int p0 = (int)(((unsigned)__float_as_int(acc[fr][fc][rg]) << 14) + (unsigned)e0);
          int p1 = (int)(((unsigned)__float_as_int(acc[fr][fc][rg + 1]) << 14) + (unsigned)(e0 - 1));
          bb = max(max(p0, p1), bb);  // v_max3_i32
        }
      }
      rbest[fc] = bb;
    }
  }
  // reduce over h (lane>>5 halves hold disjoint j, same i)
  #pragma unroll
  for (int fc = 0; fc < 4; ++fc) {
    int bb = max(rbest[fc], __shfl_xor(rbest[fc], 32, 64));
    if (l < 32) csh[w][fc * 32 + l31] = bb;
  }
  __syncthreads();
  if (t < 128) {
    int m0 = max(max(csh[0][t], csh[1][t]), max(csh[2][t], csh[3][t]));
    atomicMax(&best[ib + t], m0);
  }
}

// Final: decode best -> idx, ||z||^2 + loss, LDS-staged coalesced gather.
// 256 blocks x 256 thr; block = (b, s0) covering 32 rows.
// Loss: dist_i = ||z_i||^2 - (best>>14)*2^-20; last block writes the scalar.
// Gather: phase A reads codebook rows as 256B bursts -> tile[32][257];
// phase B writes out[b][e][s0+sl] in 128B contiguous runs (pad 257).
__global__ void k_final(const float* __restrict__ cbk, const unsigned short* __restrict__ zb,
                        const int* __restrict__ best, float* __restrict__ lossw,
                        float* __restrict__ out) {
  __shared__ float tile[32][257];
  __shared__ int lidx[32];
  __shared__ float ps[4];
  int blk = blockIdx.x, t = threadIdx.x;
  int b = blk >> 5, s0 = (blk & 31) * 32;
  int gi0 = b * 1024 + s0;
  int r8 = t >> 3, c8 = t & 7;
  int bv = best[gi0 + r8];  // 8 lanes/addr broadcast
  if (t < 32) lidx[t] = 16383 - (best[gi0 + t] & 0x3FFF);
  // ||z||^2: thread (r8,c8) covers 32 bf16 elems of row gi0+r8
  const unsigned short* zrow = zb + (size_t)(gi0 + r8) * 256 + c8 * 32;
  float ss = 0.0f;
  #pragma unroll
  for (int k = 0; k < 32; k += 4) {
    ushort4 v = *(const ushort4*)(zrow + k);
    float a0 = bf2f(v.x), a1 = bf2f(v.y), a2 = bf2f(v.z), a3 = bf2f(v.w);
    ss += a0 * a0 + a1 * a1 + a2 * a2 + a3 * a3;
  }
  ss += __shfl_xor(ss, 1, 64);
  ss += __shfl_xor(ss, 2, 64);
  ss += __shfl_xor(ss, 4, 64);
  float dist = 0.0f;
  if (c8 == 0) dist = ss - (float)(bv >> 14) * (1.0f / 1048576.0f);  // 2*score
  float v = dist;
  #pragma unroll
  for (int m = 32; m; m >>= 1) v += __shfl_down(v, m, 64);
  if ((t & 63) == 0) ps[t >> 6] = v;
  __syncthreads();
  if (t == 0) {
    float part = ps[0] + ps[1] + ps[2] + ps[3];
    atomicAdd(lossw, part);
    __threadfence();
    int cnt = atomicAdd((int*)lossw + 1, 1);
    if (cnt == 255) {
      __threadfence();
      float total = atomicAdd(lossw, 0.0f);
      out[2097152] = 1.25f * total * (1.0f / 2097152.0f);
    }
  }
  // gather (lidx is barrier-protected by the __syncthreads above)
  int w = t >> 6, l = t & 63;
  #pragma unroll
  for (int rr = 0; rr < 8; ++rr) {
    int r = w * 8 + rr;
    const float* src = cbk + (size_t)lidx[r] * 256;
    #pragma unroll
    for (int k = 0; k < 4; ++k)
      tile[r][l + 64 * k] = src[l + 64 * k];
  }
  __syncthreads();
  int sl = t & 31, eg = t >> 5;  // eg 0..7
  size_t ob = (size_t)b * 262144 + s0 + sl;
  #pragma unroll
  for (int k = 0; k < 32; ++k) {
    int e = eg + 8 * k;
    out[ob + (size_t)e * 1024] = tile[sl][e];
  }
}

extern "C" void kernel_launch(void* const* d_in, const int* in_sizes, int n_in,
                              void* d_out, int out_size, void* d_ws, size_t ws_size,
                              hipStream_t stream) {
  const float* feats  = (const float*)d_in[0];
  const float* conv_w = (const float*)d_in[1];
  const float* conv_b = (const float*)d_in[2];
  const float* cbk    = (const float*)d_in[3];
  float* out = (float*)d_out;
  char* ws = (char*)d_ws;
  // workspace layout (bytes), ~30 MB total
  unsigned short* featsT = (unsigned short*)(ws);                  // 16,777,216
  unsigned short* W2     = (unsigned short*)(ws + 16777216);       //    524,288
  unsigned short* cbs    = (unsigned short*)(ws + 17301504);       //  8,388,608
  unsigned short* zb     = (unsigned short*)(ws + 25690112);       //  4,194,304
  int*            best   = (int*)(ws + 29884416);                  //     32,768
  float*          lossw  = (float*)(ws + 29917184);                //        256

  k_prep<<<2432, 256, 0, stream>>>(cbk, conv_w, feats, cbs, W2, featsT, lossw, best);
  k_gemm1<<<dim3(4, 128), 256, 0, stream>>>(featsT, W2, conv_b, zb);
  k_gemm2<<<dim3(32, 64), 256, 0, stream>>>(cbs, zb, best);
  k_final<<<256, 256, 0, stream>>>(cbk, zb, best, lossw, out);
}

// Round 7
// 193.232 us; speedup vs baseline: 1.7231x; 1.0076x over previous
//
#include <hip/hip_runtime.h>
#include <hip/hip_bf16.h>
#include <stdint.h>

// Problem: feats[8,1024,32,32]f32, conv_w[256,1024]f32, conv_b[256]f32,
// codebook[16384,256]f32 -> z_q[8,256,32,32]f32 (2097152) + loss scalar.
//
// Round-18 design (gemm2 only; rest = r17):
//  - REAL wave stagger: co-resident blocks differ by Δby=8 (grid 2048, 2
//    blocks/CU), so the phase term must vary with by>>3 (r17's (w+bx+by)&3
//    was invariant under Δby=8 -> no-op). koff = (((by>>3)+bx)&3)*4.
//  - Named 2-ks-deep A prefetch in a windowed unroll-1 loop: next window's
//    4 A-frags issue before current window's 16 MFMAs, so the compiler
//    emits counted vmcnt (T4) and the ~200cy L2 latency hides under the
//    MFMA cluster. Named vars + unroll-1 window avoid the full-unroll /
//    array-indexed spills of r13/r14/r15. Budget: 128 AGPR acc + ~120 VGPR
//    < 256 unified cap at launch_bounds(256,2).
//  - Spill tripwire: WRITE_SIZE (must stay ~1 MB). Occupancy tripwire ~19%.

typedef float f32x4 __attribute__((ext_vector_type(4)));
typedef float f32x16 __attribute__((ext_vector_type(16)));
typedef short s16x8 __attribute__((ext_vector_type(8)));

__device__ __forceinline__ void gl2lds16(const void* g, void* l) {
  __builtin_amdgcn_global_load_lds(
      (const __attribute__((address_space(1))) void*)g,
      (__attribute__((address_space(3))) void*)l, 16, 0, 0);
}

__device__ __forceinline__ unsigned short f2bf(float f) {
  unsigned u = __float_as_uint(f);
  u = u + 0x7FFFu + ((u >> 16) & 1u);
  return (unsigned short)(u >> 16);
}
__device__ __forceinline__ float bf2f(unsigned short u) {
  return __uint_as_float(((unsigned)u) << 16);
}

__device__ __forceinline__ ushort4 cvt4(float4 v) {
  ushort4 o;
  o.x = f2bf(v.x); o.y = f2bf(v.y); o.z = f2bf(v.z); o.w = f2bf(v.w);
  return o;
}

// Fused prep, 2432 blocks x 256 thr.
// [0,256):    codebook -> cbs in 32x32x16 A-fragment order. Block jt = 64 j.
//             fl = lp*256+t in [0,2048) maps [ks 16][fr 2][lane 64]:
//             lane holds A[j=jt*64+fr*32+(lane&31)][k=ks*16+(lane>>5)*8 ..+8]
//             blocks 0-7 additionally init best[8192] = INT_MIN.
// [256,384):  conv_w -> W2 bf16, 8 elem/thread
// [384,2432): feats [8][1024 c][1024 s] -> featsT bf16 [8192 i][1024 c]
__global__ void k_prep(const float* __restrict__ cbk, const float* __restrict__ Wsrc,
                       const float* __restrict__ feats,
                       unsigned short* __restrict__ cbs, unsigned short* __restrict__ W2,
                       unsigned short* __restrict__ At, float* __restrict__ lossw,
                       int* __restrict__ best) {
  __shared__ float tile[64][65];
  int blk = blockIdx.x, t = threadIdx.x;
  if (blk == 0 && t < 2) ((int*)lossw)[t] = 0;
  if (blk < 8) {
    #pragma unroll
    for (int k = 0; k < 4; ++k) best[blk * 1024 + k * 256 + t] = (int)0x80000000;
  }
  if (blk < 256) {
    int jt = blk;
    #pragma unroll
    for (int lp = 0; lp < 8; ++lp) {
      int fl = lp * 256 + t;
      int ks = fl >> 7, fr = (fl >> 6) & 1, lane = fl & 63;
      int j = jt * 64 + fr * 32 + (lane & 31);
      int k = ks * 16 + (lane >> 5) * 8;
      const float* src = cbk + (size_t)j * 256 + k;
      float4 v0 = *(const float4*)(src);
      float4 v1 = *(const float4*)(src + 4);
      unsigned short* dst = cbs + ((size_t)jt * 2048 + fl) * 8;
      *(ushort4*)(dst) = cvt4(v0);
      *(ushort4*)(dst + 4) = cvt4(v1);
    }
  } else if (blk < 384) {
    size_t base = (size_t)(blk - 256) * 2048 + t * 8;
    float4 v0 = *(const float4*)(Wsrc + base);
    float4 v1 = *(const float4*)(Wsrc + base + 4);
    *(ushort4*)(W2 + base) = cvt4(v0);
    *(ushort4*)(W2 + base + 4) = cvt4(v1);
  } else {
    int id = blk - 384;
    int b = id >> 8, c0 = ((id >> 4) & 15) * 64, s0 = (id & 15) * 64;
    int tc = t >> 4, ts = (t & 15) * 4;
    #pragma unroll
    for (int k = 0; k < 4; ++k) {
      float4 v = *(const float4*)(feats + ((size_t)b * 1024 + c0 + tc + k * 16) * 1024 + s0 + ts);
      tile[tc + k * 16][ts] = v.x;
      tile[tc + k * 16][ts + 1] = v.y;
      tile[tc + k * 16][ts + 2] = v.z;
      tile[tc + k * 16][ts + 3] = v.w;
    }
    __syncthreads();
    #pragma unroll
    for (int k = 0; k < 4; ++k) {
      int sr = tc + k * 16;
      float4 v;
      v.x = tile[ts][sr]; v.y = tile[ts + 1][sr];
      v.z = tile[ts + 2][sr]; v.w = tile[ts + 3][sr];
      *(ushort4*)(At + (size_t)(b * 1024 + s0 + sr) * 1024 + c0 + ts) = cvt4(v);
    }
  }
}

// GEMM1: z[i][e] = sum_c feats[i][c]*W[e][c] + b[e] (K=1024 bf16) -> zb [i][256].
// BM=BN=64, BK=128 (8 kt iterations, 16 barrier drains), 4 waves 2x2
// (wave 32x32), grid (4,128). LDS 2 x 16 KB.
__global__ __launch_bounds__(256, 2)
void k_gemm1(const unsigned short* __restrict__ At, const unsigned short* __restrict__ Bw,
             const float* __restrict__ bias, unsigned short* __restrict__ zb) {
  __shared__ __align__(16) uint8_t lds[2048 * 16];
  uint8_t* ldsA = lds;
  uint8_t* ldsB = lds + 1024 * 16;
  const int t = threadIdx.x, w = t >> 6, l = t & 63;
  const int wy = w >> 1, wx = w & 1, l15 = l & 15, q = l >> 4;
  const int ib = blockIdx.y * 64, eb = blockIdx.x * 64;
  f32x4 acc[2][2] = {};
  for (int kt = 0; kt < 8; ++kt) {
    int c0 = kt * 128;
    __syncthreads();
    #pragma unroll
    for (int r = 0; r < 4; ++r) {
      int P = t + 256 * r;  // kp = P>>6 (0..15), m = P&63; LDS layout [kp][m]
      gl2lds16(At + (size_t)(ib + (P & 63)) * 1024 + c0 + (P >> 6) * 8, ldsA + P * 16);
    }
    #pragma unroll
    for (int r = 0; r < 4; ++r) {
      int P = t + 256 * r;
      gl2lds16(Bw + (size_t)(eb + (P & 63)) * 1024 + c0 + (P >> 6) * 8, ldsB + P * 16);
    }
    __syncthreads();
    #pragma unroll
    for (int s = 0; s < 4; ++s) {
      s16x8 a[2], b[2];
      #pragma unroll
      for (int fr = 0; fr < 2; ++fr)
        a[fr] = *(const s16x8*)(ldsA + ((s * 4 + q) * 64 + wy * 32 + fr * 16 + l15) * 16);
      #pragma unroll
      for (int fc = 0; fc < 2; ++fc)
        b[fc] = *(const s16x8*)(ldsB + ((s * 4 + q) * 64 + wx * 32 + fc * 16 + l15) * 16);
      #pragma unroll
      for (int fr = 0; fr < 2; ++fr)
        #pragma unroll
        for (int fc = 0; fc < 2; ++fc)
          acc[fr][fc] = __builtin_amdgcn_mfma_f32_16x16x32_bf16(a[fr], b[fc], acc[fr][fc], 0, 0, 0);
    }
  }
  #pragma unroll
  for (int fc = 0; fc < 2; ++fc) {
    int e = eb + wx * 32 + fc * 16 + l15;
    float bv = bias[e];
    #pragma unroll
    for (int fr = 0; fr < 2; ++fr)
      #pragma unroll
      for (int r = 0; r < 4; ++r) {
        int i = ib + wy * 32 + fr * 16 + q * 4 + r;
        zb[(size_t)i * 256 + e] = f2bf(acc[fr][fc][r] + bv);
      }
  }
}

// GEMM2 + argmax, 32x32x16 j-stream. A = cbs (fragment order),
// B = zb [8192 i][256]. 256 thr / 4 waves, i-tile 128 (64 KB LDS, 1 barrier).
// Wave tile 64j x 128i: acc[2][4] = 128 AGPR, launch_bounds(256,2).
// Pipelining: named 2-ks-deep A prefetch in an unroll-1 window loop (next
// window's 4 frags issue before this window's 16 MFMAs -> counted vmcnt).
// Stagger: koff = (((by>>3)+bx)&3)*4 differs between co-resident blocks
// (Δby=8), so same-SIMD waves run anti-phase K sweeps.
// Fold: p = (bits(3.0+s)<<14) + (16383-j); paired -> v_max3_i32;
// atomicMax into best[8192] (monotone int encoding).
__global__ __launch_bounds__(256, 2)
void k_gemm2(const unsigned short* __restrict__ cbs, const unsigned short* __restrict__ zb,
             int* __restrict__ best) {
  __shared__ __align__(16) uint8_t ldsB[65536];  // 64 KB: [kp 32][i 128][8 bf16]
  __shared__ int csh[4][128];
  const int t = threadIdx.x, w = t >> 6, l = t & 63;
  const int l31 = l & 31, h = l >> 5;
  const int ib = blockIdx.y * 128;
  // stage zb tile once: packet P -> i = P&127, kp = P>>7
  #pragma unroll
  for (int r = 0; r < 16; ++r) {
    int P = t + 256 * r;
    gl2lds16(zb + (size_t)(ib + (P & 127)) * 256 + (P >> 7) * 8, ldsB + P * 16);
  }
  int rbest[4];
  #pragma unroll
  for (int fc = 0; fc < 4; ++fc) rbest[fc] = (int)0x80000000;
  // anti-phase between co-resident blocks: Δby=8 -> Δ(by>>3)=1 -> Δkoff=4
  const int koff = (((blockIdx.y >> 3) + blockIdx.x) & 3) * 4;
  __syncthreads();
  const uint8_t* bbase = ldsB + (h * 128 + l31) * 16;  // + ks*4096 + fc*512
  #pragma unroll 1
  for (int js = 0; js < 2; ++js) {
    const int jtile = blockIdx.x * 8 + js * 4 + w;  // 64-j tile index
    const int jw = jtile * 64;
    const uint8_t* abase = (const uint8_t*)cbs + (size_t)jtile * 32768 + l * 16;
    f32x16 acc[2][4];  // [fr j-half][fc i-quarter], pre-biased at 3.0
    #pragma unroll
    for (int fr = 0; fr < 2; ++fr)
      #pragma unroll
      for (int fc = 0; fc < 4; ++fc)
        #pragma unroll
        for (int rg = 0; rg < 16; ++rg)
          acc[fr][fc][rg] = 3.0f;
    // prologue: A frags for window 0 (ks = koff, koff+1)
    s16x8 a00 = *(const s16x8*)(abase + (koff * 2) * 1024);
    s16x8 a01 = *(const s16x8*)(abase + (koff * 2 + 1) * 1024);
    s16x8 a10 = *(const s16x8*)(abase + (((koff + 1) & 15) * 2) * 1024);
    s16x8 a11 = *(const s16x8*)(abase + (((koff + 1) & 15) * 2 + 1) * 1024);
    #pragma unroll 1
    for (int kw = 0; kw < 16; kw += 2) {
      const int ksA = (kw + koff) & 15;
      const int ksB = (kw + 1 + koff) & 15;
      const int ksN0 = (kw + 2 + koff) & 15;  // wraps to koff on last iter (harmless reload)
      const int ksN1 = (kw + 3 + koff) & 15;
      // issue next window's A loads first (stay in flight across the MFMAs)
      s16x8 n00 = *(const s16x8*)(abase + (ksN0 * 2) * 1024);
      s16x8 n01 = *(const s16x8*)(abase + (ksN0 * 2 + 1) * 1024);
      s16x8 n10 = *(const s16x8*)(abase + (ksN1 * 2) * 1024);
      s16x8 n11 = *(const s16x8*)(abase + (ksN1 * 2 + 1) * 1024);
      // window's B frags
      const uint8_t* bpA = bbase + ksA * 4096;
      const uint8_t* bpB = bbase + ksB * 4096;
      s16x8 b0 = *(const s16x8*)(bpA);
      s16x8 b1 = *(const s16x8*)(bpA + 512);
      s16x8 b2 = *(const s16x8*)(bpA + 1024);
      s16x8 b3 = *(const s16x8*)(bpA + 1536);
      s16x8 c0 = *(const s16x8*)(bpB);
      s16x8 c1 = *(const s16x8*)(bpB + 512);
      s16x8 c2 = *(const s16x8*)(bpB + 1024);
      s16x8 c3 = *(const s16x8*)(bpB + 1536);
      // MFMAs for ksA (a00/a01 resident since last iteration)
      acc[0][0] = __builtin_amdgcn_mfma_f32_32x32x16_bf16(a00, b0, acc[0][0], 0, 0, 0);
      acc[1][0] = __builtin_amdgcn_mfma_f32_32x32x16_bf16(a01, b0, acc[1][0], 0, 0, 0);
      acc[0][1] = __builtin_amdgcn_mfma_f32_32x32x16_bf16(a00, b1, acc[0][1], 0, 0, 0);
      acc[1][1] = __builtin_amdgcn_mfma_f32_32x32x16_bf16(a01, b1, acc[1][1], 0, 0, 0);
      acc[0][2] = __builtin_amdgcn_mfma_f32_32x32x16_bf16(a00, b2, acc[0][2], 0, 0, 0);
      acc[1][2] = __builtin_amdgcn_mfma_f32_32x32x16_bf16(a01, b2, acc[1][2], 0, 0, 0);
      acc[0][3] = __builtin_amdgcn_mfma_f32_32x32x16_bf16(a00, b3, acc[0][3], 0, 0, 0);
      acc[1][3] = __builtin_amdgcn_mfma_f32_32x32x16_bf16(a01, b3, acc[1][3], 0, 0, 0);
      // MFMAs for ksB
      acc[0][0] = __builtin_amdgcn_mfma_f32_32x32x16_bf16(a10, c0, acc[0][0], 0, 0, 0);
      acc[1][0] = __builtin_amdgcn_mfma_f32_32x32x16_bf16(a11, c0, acc[1][0], 0, 0, 0);
      acc[0][1] = __builtin_amdgcn_mfma_f32_32x32x16_bf16(a10, c1, acc[0][1], 0, 0, 0);
      acc[1][1] = __builtin_amdgcn_mfma_f32_32x32x16_bf16(a11, c1, acc[1][1], 0, 0, 0);
      acc[0][2] = __builtin_amdgcn_mfma_f32_32x32x16_bf16(a10, c2, acc[0][2], 0, 0, 0);
      acc[1][2] = __builtin_amdgcn_mfma_f32_32x32x16_bf16(a11, c2, acc[1][2], 0, 0, 0);
      acc[0][3] = __builtin_amdgcn_mfma_f32_32x32x16_bf16(a10, c3, acc[0][3], 0, 0, 0);
      acc[1][3] = __builtin_amdgcn_mfma_f32_32x32x16_bf16(a11, c3, acc[1][3], 0, 0, 0);
      // rotate (pure register renames)
      a00 = n00; a01 = n01; a10 = n10; a11 = n11;
    }
    // fold: j = jw + fr*32 + (rg&3) + 8*(rg>>2) + 4*h ; i = ib + fc*32 + l31
    const int encb = 16383 - (jw + 4 * h);
    #pragma unroll
    for (int fc = 0; fc < 4; ++fc) {
      int bb = rbest[fc];
      #pragma unroll
      for (int fr = 0; fr < 2; ++fr) {
        const int e1 = encb - fr * 32;
        #pragma unroll
        for (int rg = 0; rg < 16; rg += 2) {
          int e0 = e1 - ((rg & 3) + 8 * (rg >> 2));  // rg even; rg+1 -> e0-1
          int p0 = (int)(((unsigned)__float_as_int(acc[fr][fc][rg]) << 14) + (unsigned)e0);
          int p1 = (int)(((unsigned)__float_as_int(acc[fr][fc][rg + 1]) << 14) + (unsigned)(e0 - 1));
          bb = max(max(p0, p1), bb);  // v_max3_i32
        }
      }
      rbest[fc] = bb;
    }
  }
  // reduce over h (lane>>5 halves hold disjoint j, same i)
  #pragma unroll
  for (int fc = 0; fc < 4; ++fc) {
    int bb = max(rbest[fc], __shfl_xor(rbest[fc], 32, 64));
    if (l < 32) csh[w][fc * 32 + l31] = bb;
  }
  __syncthreads();
  if (t < 128) {
    int m0 = max(max(csh[0][t], csh[1][t]), max(csh[2][t], csh[3][t]));
    atomicMax(&best[ib + t], m0);
  }
}

// Final: decode best -> idx, ||z||^2 + loss, LDS-staged coalesced gather.
// 256 blocks x 256 thr; block = (b, s0) covering 32 rows.
// Loss: dist_i = ||z_i||^2 - (best>>14)*2^-20; last block writes the scalar.
// Gather: phase A reads codebook rows as 256B bursts -> tile[32][257];
// phase B writes out[b][e][s0+sl] in 128B contiguous runs (pad 257).
__global__ void k_final(const float* __restrict__ cbk, const unsigned short* __restrict__ zb,
                        const int* __restrict__ best, float* __restrict__ lossw,
                        float* __restrict__ out) {
  __shared__ float tile[32][257];
  __shared__ int lidx[32];
  __shared__ float ps[4];
  int blk = blockIdx.x, t = threadIdx.x;
  int b = blk >> 5, s0 = (blk & 31) * 32;
  int gi0 = b * 1024 + s0;
  int r8 = t >> 3, c8 = t & 7;
  int bv = best[gi0 + r8];  // 8 lanes/addr broadcast
  if (t < 32) lidx[t] = 16383 - (best[gi0 + t] & 0x3FFF);
  // ||z||^2: thread (r8,c8) covers 32 bf16 elems of row gi0+r8
  const unsigned short* zrow = zb + (size_t)(gi0 + r8) * 256 + c8 * 32;
  float ss = 0.0f;
  #pragma unroll
  for (int k = 0; k < 32; k += 4) {
    ushort4 v = *(const ushort4*)(zrow + k);
    float a0 = bf2f(v.x), a1 = bf2f(v.y), a2 = bf2f(v.z), a3 = bf2f(v.w);
    ss += a0 * a0 + a1 * a1 + a2 * a2 + a3 * a3;
  }
  ss += __shfl_xor(ss, 1, 64);
  ss += __shfl_xor(ss, 2, 64);
  ss += __shfl_xor(ss, 4, 64);
  float dist = 0.0f;
  if (c8 == 0) dist = ss - (float)(bv >> 14) * (1.0f / 1048576.0f);  // 2*score
  float v = dist;
  #pragma unroll
  for (int m = 32; m; m >>= 1) v += __shfl_down(v, m, 64);
  if ((t & 63) == 0) ps[t >> 6] = v;
  __syncthreads();
  if (t == 0) {
    float part = ps[0] + ps[1] + ps[2] + ps[3];
    atomicAdd(lossw, part);
    __threadfence();
    int cnt = atomicAdd((int*)lossw + 1, 1);
    if (cnt == 255) {
      __threadfence();
      float total = atomicAdd(lossw, 0.0f);
      out[2097152] = 1.25f * total * (1.0f / 2097152.0f);
    }
  }
  // gather (lidx is barrier-protected by the __syncthreads above)
  int w = t >> 6, l = t & 63;
  #pragma unroll
  for (int rr = 0; rr < 8; ++rr) {
    int r = w * 8 + rr;
    const float* src = cbk + (size_t)lidx[r] * 256;
    #pragma unroll
    for (int k = 0; k < 4; ++k)
      tile[r][l + 64 * k] = src[l + 64 * k];
  }
  __syncthreads();
  int sl = t & 31, eg = t >> 5;  // eg 0..7
  size_t ob = (size_t)b * 262144 + s0 + sl;
  #pragma unroll
  for (int k = 0; k < 32; ++k) {
    int e = eg + 8 * k;
    out[ob + (size_t)e * 1024] = tile[sl][e];
  }
}

extern "C" void kernel_launch(void* const* d_in, const int* in_sizes, int n_in,
                              void* d_out, int out_size, void* d_ws, size_t ws_size,
                              hipStream_t stream) {
  const float* feats  = (const float*)d_in[0];
  const float* conv_w = (const float*)d_in[1];
  const float* conv_b = (const float*)d_in[2];
  const float* cbk    = (const float*)d_in[3];
  float* out = (float*)d_out;
  char* ws = (char*)d_ws;
  // workspace layout (bytes), ~30 MB total
  unsigned short* featsT = (unsigned short*)(ws);                  // 16,777,216
  unsigned short* W2     = (unsigned short*)(ws + 16777216);       //    524,288
  unsigned short* cbs    = (unsigned short*)(ws + 17301504);       //  8,388,608
  unsigned short* zb     = (unsigned short*)(ws + 25690112);       //  4,194,304
  int*            best   = (int*)(ws + 29884416);                  //     32,768
  float*          lossw  = (float*)(ws + 29917184);                //        256

  k_prep<<<2432, 256, 0, stream>>>(cbk, conv_w, feats, cbs, W2, featsT, lossw, best);
  k_gemm1<<<dim3(4, 128), 256, 0, stream>>>(featsT, W2, conv_b, zb);
  k_gemm2<<<dim3(32, 64), 256, 0, stream>>>(cbs, zb, best);
  k_final<<<256, 256, 0, stream>>>(cbk, zb, best, lossw, out);
}

// Round 8
// 165.737 us; speedup vs baseline: 2.0090x; 1.1659x over previous
//
#include <hip/hip_runtime.h>
#include <hip/hip_bf16.h>
#include <stdint.h>

// Problem: feats[8,1024,32,32]f32, conv_w[256,1024]f32, conv_b[256]f32,
// codebook[16384,256]f32 -> z_q[8,256,32,32]f32 (2097152) + loss scalar.
//
// Round-19 design:
//  - gemm2 in INT8: mfma_i32_32x32x32_i8 (2x bf16 rate, K=32). r11-r18 showed
//    MfmaUtil pinned at 35-38% across every geometry/pipelining variant (the
//    plain-HIP 2-barrier plateau); i8 halves both operand bytes and MFMA
//    cycles, so the same util ratio = half the time.
//    Quantization: codebook U(+-1/16384) -> e8 = rn(e*127*16384), exact-range;
//    z ~ N(0,1) -> z8 = clamp(rn(z*16), +-127). Int accumulation exact; score
//    error ~2% of score sigma (bf16 path was ~1%); mispicks bounded by
//    codebook range = 1.2e-4 (the absmax we already measure).
//    Loss/fold: reconstruct float score sf = fma(cvt(acc), 1/(16*127*16384),
//    3.0) and reuse the EXISTING bit-encode/decode unchanged.
//    Layout: A and B built with identical k-placement (lane&31 = row/col,
//    (lane>>5)*16 +[0..16) = k bytes); MFMA dot is invariant under a common
//    k-permutation of both operands, so only the verified row/col mapping
//    matters.
//  - 4 launches: prep, gemm1 (+z8 epilogue), gemm2(i8), final.

typedef float f32x4 __attribute__((ext_vector_type(4)));
typedef int i32x4 __attribute__((ext_vector_type(4)));
typedef int i32x16 __attribute__((ext_vector_type(16)));
typedef short s16x8 __attribute__((ext_vector_type(8)));

__device__ __forceinline__ void gl2lds16(const void* g, void* l) {
  __builtin_amdgcn_global_load_lds(
      (const __attribute__((address_space(1))) void*)g,
      (__attribute__((address_space(3))) void*)l, 16, 0, 0);
}

__device__ __forceinline__ unsigned short f2bf(float f) {
  unsigned u = __float_as_uint(f);
  u = u + 0x7FFFu + ((u >> 16) & 1u);
  return (unsigned short)(u >> 16);
}
__device__ __forceinline__ float bf2f(unsigned short u) {
  return __uint_as_float(((unsigned)u) << 16);
}

__device__ __forceinline__ ushort4 cvt4(float4 v) {
  ushort4 o;
  o.x = f2bf(v.x); o.y = f2bf(v.y); o.z = f2bf(v.z); o.w = f2bf(v.w);
  return o;
}

// Fused prep, 2432 blocks x 256 thr.
// [0,256):    codebook -> cbs8 (i8, scale 127*16384) in 32x32x32 A-fragment
//             order. Block jt = 64 j. fl = lp*256+t in [0,1024) maps
//             [ks 8][fr 2][lane 64]: lane holds
//             A[j=jt*64+fr*32+(lane&31)][k=ks*32+(lane>>5)*16 ..+16]
//             blocks 0-7 additionally init best[8192] = INT_MIN.
// [256,384):  conv_w -> W2 bf16, 8 elem/thread
// [384,2432): feats [8][1024 c][1024 s] -> featsT bf16 [8192 i][1024 c]
__global__ void k_prep(const float* __restrict__ cbk, const float* __restrict__ Wsrc,
                       const float* __restrict__ feats,
                       signed char* __restrict__ cbs8, unsigned short* __restrict__ W2,
                       unsigned short* __restrict__ At, float* __restrict__ lossw,
                       int* __restrict__ best) {
  __shared__ float tile[64][65];
  int blk = blockIdx.x, t = threadIdx.x;
  if (blk == 0 && t < 2) ((int*)lossw)[t] = 0;
  if (blk < 8) {
    #pragma unroll
    for (int k = 0; k < 4; ++k) best[blk * 1024 + k * 256 + t] = (int)0x80000000;
  }
  if (blk < 256) {
    int jt = blk;
    #pragma unroll
    for (int lp = 0; lp < 4; ++lp) {
      int fl = lp * 256 + t;  // [0,1024)
      int ks = fl >> 7, fr = (fl >> 6) & 1, lane = fl & 63;
      int j = jt * 64 + fr * 32 + (lane & 31);
      int k = ks * 32 + (lane >> 5) * 16;
      const float* src = cbk + (size_t)j * 256 + k;
      int w4[4];
      #pragma unroll
      for (int q4 = 0; q4 < 4; ++q4) {
        float4 v = *(const float4*)(src + q4 * 4);
        int b0 = __float2int_rn(v.x * 2080768.0f);  // 127*16384
        int b1 = __float2int_rn(v.y * 2080768.0f);
        int b2 = __float2int_rn(v.z * 2080768.0f);
        int b3 = __float2int_rn(v.w * 2080768.0f);
        w4[q4] = (b0 & 255) | ((b1 & 255) << 8) | ((b2 & 255) << 16) | ((b3 & 255) << 24);
      }
      int4* dst = (int4*)(cbs8 + (size_t)jt * 16384 + (size_t)fl * 16);
      *dst = make_int4(w4[0], w4[1], w4[2], w4[3]);
    }
  } else if (blk < 384) {
    size_t base = (size_t)(blk - 256) * 2048 + t * 8;
    float4 v0 = *(const float4*)(Wsrc + base);
    float4 v1 = *(const float4*)(Wsrc + base + 4);
    *(ushort4*)(W2 + base) = cvt4(v0);
    *(ushort4*)(W2 + base + 4) = cvt4(v1);
  } else {
    int id = blk - 384;
    int b = id >> 8, c0 = ((id >> 4) & 15) * 64, s0 = (id & 15) * 64;
    int tc = t >> 4, ts = (t & 15) * 4;
    #pragma unroll
    for (int k = 0; k < 4; ++k) {
      float4 v = *(const float4*)(feats + ((size_t)b * 1024 + c0 + tc + k * 16) * 1024 + s0 + ts);
      tile[tc + k * 16][ts] = v.x;
      tile[tc + k * 16][ts + 1] = v.y;
      tile[tc + k * 16][ts + 2] = v.z;
      tile[tc + k * 16][ts + 3] = v.w;
    }
    __syncthreads();
    #pragma unroll
    for (int k = 0; k < 4; ++k) {
      int sr = tc + k * 16;
      float4 v;
      v.x = tile[ts][sr]; v.y = tile[ts + 1][sr];
      v.z = tile[ts + 2][sr]; v.w = tile[ts + 3][sr];
      *(ushort4*)(At + (size_t)(b * 1024 + s0 + sr) * 1024 + c0 + ts) = cvt4(v);
    }
  }
}

// GEMM1: z[i][e] = sum_c feats[i][c]*W[e][c] + b[e] (K=1024 bf16) -> zb [i][256]
// bf16 (for ||z||^2 in k_final) + z8 [i][256] i8 (scale 16, for gemm2).
// BM=BN=64, BK=128, 4 waves 2x2 (wave 32x32), grid (4,128). LDS 2 x 16 KB.
__global__ __launch_bounds__(256, 2)
void k_gemm1(const unsigned short* __restrict__ At, const unsigned short* __restrict__ Bw,
             const float* __restrict__ bias, unsigned short* __restrict__ zb,
             signed char* __restrict__ z8) {
  __shared__ __align__(16) uint8_t lds[2048 * 16];
  uint8_t* ldsA = lds;
  uint8_t* ldsB = lds + 1024 * 16;
  const int t = threadIdx.x, w = t >> 6, l = t & 63;
  const int wy = w >> 1, wx = w & 1, l15 = l & 15, q = l >> 4;
  const int ib = blockIdx.y * 64, eb = blockIdx.x * 64;
  f32x4 acc[2][2] = {};
  for (int kt = 0; kt < 8; ++kt) {
    int c0 = kt * 128;
    __syncthreads();
    #pragma unroll
    for (int r = 0; r < 4; ++r) {
      int P = t + 256 * r;  // kp = P>>6 (0..15), m = P&63; LDS layout [kp][m]
      gl2lds16(At + (size_t)(ib + (P & 63)) * 1024 + c0 + (P >> 6) * 8, ldsA + P * 16);
    }
    #pragma unroll
    for (int r = 0; r < 4; ++r) {
      int P = t + 256 * r;
      gl2lds16(Bw + (size_t)(eb + (P & 63)) * 1024 + c0 + (P >> 6) * 8, ldsB + P * 16);
    }
    __syncthreads();
    #pragma unroll
    for (int s = 0; s < 4; ++s) {
      s16x8 a[2], b[2];
      #pragma unroll
      for (int fr = 0; fr < 2; ++fr)
        a[fr] = *(const s16x8*)(ldsA + ((s * 4 + q) * 64 + wy * 32 + fr * 16 + l15) * 16);
      #pragma unroll
      for (int fc = 0; fc < 2; ++fc)
        b[fc] = *(const s16x8*)(ldsB + ((s * 4 + q) * 64 + wx * 32 + fc * 16 + l15) * 16);
      #pragma unroll
      for (int fr = 0; fr < 2; ++fr)
        #pragma unroll
        for (int fc = 0; fc < 2; ++fc)
          acc[fr][fc] = __builtin_amdgcn_mfma_f32_16x16x32_bf16(a[fr], b[fc], acc[fr][fc], 0, 0, 0);
    }
  }
  #pragma unroll
  for (int fc = 0; fc < 2; ++fc) {
    int e = eb + wx * 32 + fc * 16 + l15;
    float bv = bias[e];
    #pragma unroll
    for (int fr = 0; fr < 2; ++fr)
      #pragma unroll
      for (int r = 0; r < 4; ++r) {
        int i = ib + wy * 32 + fr * 16 + q * 4 + r;
        float zf = acc[fr][fc][r] + bv;
        zb[(size_t)i * 256 + e] = f2bf(zf);
        int qv = __float2int_rn(zf * 16.0f);
        qv = qv > 127 ? 127 : (qv < -127 ? -127 : qv);
        z8[(size_t)i * 256 + e] = (signed char)qv;
      }
  }
}

// GEMM2 + argmax in INT8, 32x32x32 j-stream. A = cbs8 (fragment order),
// B = z8 [8192 i][256] staged in LDS (32 KB). 256 thr / 4 waves, i-tile 128.
// Wave tile 64j x 128i: acc[2][4] = 128 AGPR, launch_bounds(256,2), 8 ks
// steps (K=32 each), unroll 2 (unroll discipline: wider windows spill).
// Fold: sf = fma(cvt(acc), 1/(16*127*16384), 3.0) then the UNCHANGED
// bit-encode p = (bits(sf)<<14)+(16383-j); paired v_max3; atomicMax output.
__global__ __launch_bounds__(256, 2)
void k_gemm2(const signed char* __restrict__ cbs8, const signed char* __restrict__ z8,
             int* __restrict__ best) {
  __shared__ __align__(16) uint8_t ldsB[32768];  // [kseg 16][i 128][16B]
  __shared__ int csh[4][128];
  const int t = threadIdx.x, w = t >> 6, l = t & 63;
  const int l31 = l & 31, h = l >> 5;
  const int ib = blockIdx.y * 128;
  // stage z8 tile: packet P -> i = P&127, kseg = P>>7 (16B per packet)
  #pragma unroll
  for (int r = 0; r < 8; ++r) {
    int P = t + 256 * r;
    gl2lds16(z8 + (size_t)(ib + (P & 127)) * 256 + (P >> 7) * 16, ldsB + P * 16);
  }
  int rbest[4];
  #pragma unroll
  for (int fc = 0; fc < 4; ++fc) rbest[fc] = (int)0x80000000;
  __syncthreads();
  const uint8_t* bbase = ldsB + (h * 128 + l31) * 16;  // + ks*4096 + fc*512
  const float inv = 1.0f / 33292288.0f;  // 1/(16*127*16384)
  #pragma unroll 1
  for (int js = 0; js < 2; ++js) {
    const int jtile = blockIdx.x * 8 + js * 4 + w;  // 64-j tile index
    const int jw = jtile * 64;
    const uint8_t* abase = (const uint8_t*)cbs8 + (size_t)jtile * 16384 + l * 16;
    i32x16 acc[2][4] = {};  // [fr j-half][fc i-quarter]
    #pragma unroll 2
    for (int ks = 0; ks < 8; ++ks) {
      i32x4 a0 = *(const i32x4*)(abase + (ks * 2) * 1024);
      i32x4 a1 = *(const i32x4*)(abase + (ks * 2 + 1) * 1024);
      i32x4 b0 = *(const i32x4*)(bbase + ks * 4096);
      i32x4 b1 = *(const i32x4*)(bbase + ks * 4096 + 512);
      i32x4 b2 = *(const i32x4*)(bbase + ks * 4096 + 1024);
      i32x4 b3 = *(const i32x4*)(bbase + ks * 4096 + 1536);
      acc[0][0] = __builtin_amdgcn_mfma_i32_32x32x32_i8(a0, b0, acc[0][0], 0, 0, 0);
      acc[1][0] = __builtin_amdgcn_mfma_i32_32x32x32_i8(a1, b0, acc[1][0], 0, 0, 0);
      acc[0][1] = __builtin_amdgcn_mfma_i32_32x32x32_i8(a0, b1, acc[0][1], 0, 0, 0);
      acc[1][1] = __builtin_amdgcn_mfma_i32_32x32x32_i8(a1, b1, acc[1][1], 0, 0, 0);
      acc[0][2] = __builtin_amdgcn_mfma_i32_32x32x32_i8(a0, b2, acc[0][2], 0, 0, 0);
      acc[1][2] = __builtin_amdgcn_mfma_i32_32x32x32_i8(a1, b2, acc[1][2], 0, 0, 0);
      acc[0][3] = __builtin_amdgcn_mfma_i32_32x32x32_i8(a0, b3, acc[0][3], 0, 0, 0);
      acc[1][3] = __builtin_amdgcn_mfma_i32_32x32x32_i8(a1, b3, acc[1][3], 0, 0, 0);
    }
    // fold: j = jw + fr*32 + (rg&3) + 8*(rg>>2) + 4*h ; i = ib + fc*32 + l31
    const int encb = 16383 - (jw + 4 * h);
    #pragma unroll
    for (int fc = 0; fc < 4; ++fc) {
      int bb = rbest[fc];
      #pragma unroll
      for (int fr = 0; fr < 2; ++fr) {
        const int e1 = encb - fr * 32;
        #pragma unroll
        for (int rg = 0; rg < 16; rg += 2) {
          int e0 = e1 - ((rg & 3) + 8 * (rg >> 2));  // rg even; rg+1 -> e0-1
          float s0 = fmaf((float)acc[fr][fc][rg], inv, 3.0f);
          float s1 = fmaf((float)acc[fr][fc][rg + 1], inv, 3.0f);
          int p0 = (int)(((unsigned)__float_as_int(s0) << 14) + (unsigned)e0);
          int p1 = (int)(((unsigned)__float_as_int(s1) << 14) + (unsigned)(e0 - 1));
          bb = max(max(p0, p1), bb);  // v_max3_i32
        }
      }
      rbest[fc] = bb;
    }
  }
  // reduce over h (lane>>5 halves hold disjoint j, same i)
  #pragma unroll
  for (int fc = 0; fc < 4; ++fc) {
    int bb = max(rbest[fc], __shfl_xor(rbest[fc], 32, 64));
    if (l < 32) csh[w][fc * 32 + l31] = bb;
  }
  __syncthreads();
  if (t < 128) {
    int m0 = max(max(csh[0][t], csh[1][t]), max(csh[2][t], csh[3][t]));
    atomicMax(&best[ib + t], m0);
  }
}

// Final: decode best -> idx, ||z||^2 + loss, LDS-staged coalesced gather.
// 256 blocks x 256 thr; block = (b, s0) covering 32 rows.
// Loss: dist_i = ||z_i||^2 - (best>>14)*2^-20; last block writes the scalar.
// Gather: phase A reads codebook rows as 256B bursts -> tile[32][257];
// phase B writes out[b][e][s0+sl] in 128B contiguous runs (pad 257).
__global__ void k_final(const float* __restrict__ cbk, const unsigned short* __restrict__ zb,
                        const int* __restrict__ best, float* __restrict__ lossw,
                        float* __restrict__ out) {
  __shared__ float tile[32][257];
  __shared__ int lidx[32];
  __shared__ float ps[4];
  int blk = blockIdx.x, t = threadIdx.x;
  int b = blk >> 5, s0 = (blk & 31) * 32;
  int gi0 = b * 1024 + s0;
  int r8 = t >> 3, c8 = t & 7;
  int bv = best[gi0 + r8];  // 8 lanes/addr broadcast
  if (t < 32) lidx[t] = 16383 - (best[gi0 + t] & 0x3FFF);
  // ||z||^2: thread (r8,c8) covers 32 bf16 elems of row gi0+r8
  const unsigned short* zrow = zb + (size_t)(gi0 + r8) * 256 + c8 * 32;
  float ss = 0.0f;
  #pragma unroll
  for (int k = 0; k < 32; k += 4) {
    ushort4 v = *(const ushort4*)(zrow + k);
    float a0 = bf2f(v.x), a1 = bf2f(v.y), a2 = bf2f(v.z), a3 = bf2f(v.w);
    ss += a0 * a0 + a1 * a1 + a2 * a2 + a3 * a3;
  }
  ss += __shfl_xor(ss, 1, 64);
  ss += __shfl_xor(ss, 2, 64);
  ss += __shfl_xor(ss, 4, 64);
  float dist = 0.0f;
  if (c8 == 0) dist = ss - (float)(bv >> 14) * (1.0f / 1048576.0f);  // 2*score
  float v = dist;
  #pragma unroll
  for (int m = 32; m; m >>= 1) v += __shfl_down(v, m, 64);
  if ((t & 63) == 0) ps[t >> 6] = v;
  __syncthreads();
  if (t == 0) {
    float part = ps[0] + ps[1] + ps[2] + ps[3];
    atomicAdd(lossw, part);
    __threadfence();
    int cnt = atomicAdd((int*)lossw + 1, 1);
    if (cnt == 255) {
      __threadfence();
      float total = atomicAdd(lossw, 0.0f);
      out[2097152] = 1.25f * total * (1.0f / 2097152.0f);
    }
  }
  // gather (lidx is barrier-protected by the __syncthreads above)
  int w = t >> 6, l = t & 63;
  #pragma unroll
  for (int rr = 0; rr < 8; ++rr) {
    int r = w * 8 + rr;
    const float* src = cbk + (size_t)lidx[r] * 256;
    #pragma unroll
    for (int k = 0; k < 4; ++k)
      tile[r][l + 64 * k] = src[l + 64 * k];
  }
  __syncthreads();
  int sl = t & 31, eg = t >> 5;  // eg 0..7
  size_t ob = (size_t)b * 262144 + s0 + sl;
  #pragma unroll
  for (int k = 0; k < 32; ++k) {
    int e = eg + 8 * k;
    out[ob + (size_t)e * 1024] = tile[sl][e];
  }
}

extern "C" void kernel_launch(void* const* d_in, const int* in_sizes, int n_in,
                              void* d_out, int out_size, void* d_ws, size_t ws_size,
                              hipStream_t stream) {
  const float* feats  = (const float*)d_in[0];
  const float* conv_w = (const float*)d_in[1];
  const float* conv_b = (const float*)d_in[2];
  const float* cbk    = (const float*)d_in[3];
  float* out = (float*)d_out;
  char* ws = (char*)d_ws;
  // workspace layout (bytes), ~28 MB total
  unsigned short* featsT = (unsigned short*)(ws);                  // 16,777,216
  unsigned short* W2     = (unsigned short*)(ws + 16777216);       //    524,288
  signed char*    cbs8   = (signed char*)(ws + 17301504);          //  4,194,304
  unsigned short* zb     = (unsigned short*)(ws + 21495808);       //  4,194,304
  signed char*    z8     = (signed char*)(ws + 25690112);          //  2,097,152
  int*            best   = (int*)(ws + 27787264);                  //     32,768
  float*          lossw  = (float*)(ws + 27820032);                //        256

  k_prep<<<2432, 256, 0, stream>>>(cbk, conv_w, feats, cbs8, W2, featsT, lossw, best);
  k_gemm1<<<dim3(4, 128), 256, 0, stream>>>(featsT, W2, conv_b, zb, z8);
  k_gemm2<<<dim3(32, 64), 256, 0, stream>>>(cbs8, z8, best);
  k_final<<<256, 256, 0, stream>>>(cbk, zb, best, lossw, out);
}

// Round 9
// 162.726 us; speedup vs baseline: 2.0461x; 1.0185x over previous
//
#include <hip/hip_runtime.h>
#include <hip/hip_bf16.h>
#include <stdint.h>

// Problem: feats[8,1024,32,32]f32, conv_w[256,1024]f32, conv_b[256]f32,
// codebook[16384,256]f32 -> z_q[8,256,32,32]f32 (2097152) + loss scalar.
//
// Round-20 design (gemm2 fold only; rest = r19):
//  - INT fold: i32 acc is an exact monotone score. Per-thread candidate set
//    per output i is 64 slots (9 bits incl js); |acc| <= 256*127^2 < 2^22 so
//    p = (acc<<9) + (511-slot) fits int32 exactly. 1.5 VALU/score (lshl_add
//    pairs + v_max3) vs r19's 3.5 (cvt+fma per score). Winner decoded ONCE
//    per fc: acc = p>>9, j = bx*512+w*64+4h+(511-(p&511)), then the
//    unchanged float bit-encode feeds the existing csh/atomicMax path.
//    r19 counters: VALUBusy 43% > MfmaUtil 30% -> fold was the critical path.
//  - 4 launches: prep, gemm1 (+z8 epilogue), gemm2(i8), final.

typedef float f32x4 __attribute__((ext_vector_type(4)));
typedef int i32x4 __attribute__((ext_vector_type(4)));
typedef int i32x16 __attribute__((ext_vector_type(16)));
typedef short s16x8 __attribute__((ext_vector_type(8)));

__device__ __forceinline__ void gl2lds16(const void* g, void* l) {
  __builtin_amdgcn_global_load_lds(
      (const __attribute__((address_space(1))) void*)g,
      (__attribute__((address_space(3))) void*)l, 16, 0, 0);
}

__device__ __forceinline__ unsigned short f2bf(float f) {
  unsigned u = __float_as_uint(f);
  u = u + 0x7FFFu + ((u >> 16) & 1u);
  return (unsigned short)(u >> 16);
}
__device__ __forceinline__ float bf2f(unsigned short u) {
  return __uint_as_float(((unsigned)u) << 16);
}

__device__ __forceinline__ ushort4 cvt4(float4 v) {
  ushort4 o;
  o.x = f2bf(v.x); o.y = f2bf(v.y); o.z = f2bf(v.z); o.w = f2bf(v.w);
  return o;
}

// Fused prep, 2432 blocks x 256 thr.
// [0,256):    codebook -> cbs8 (i8, scale 127*16384) in 32x32x32 A-fragment
//             order. Block jt = 64 j. fl = lp*256+t in [0,1024) maps
//             [ks 8][fr 2][lane 64]: lane holds
//             A[j=jt*64+fr*32+(lane&31)][k=ks*32+(lane>>5)*16 ..+16]
//             blocks 0-7 additionally init best[8192] = INT_MIN.
// [256,384):  conv_w -> W2 bf16, 8 elem/thread
// [384,2432): feats [8][1024 c][1024 s] -> featsT bf16 [8192 i][1024 c]
__global__ void k_prep(const float* __restrict__ cbk, const float* __restrict__ Wsrc,
                       const float* __restrict__ feats,
                       signed char* __restrict__ cbs8, unsigned short* __restrict__ W2,
                       unsigned short* __restrict__ At, float* __restrict__ lossw,
                       int* __restrict__ best) {
  __shared__ float tile[64][65];
  int blk = blockIdx.x, t = threadIdx.x;
  if (blk == 0 && t < 2) ((int*)lossw)[t] = 0;
  if (blk < 8) {
    #pragma unroll
    for (int k = 0; k < 4; ++k) best[blk * 1024 + k * 256 + t] = (int)0x80000000;
  }
  if (blk < 256) {
    int jt = blk;
    #pragma unroll
    for (int lp = 0; lp < 4; ++lp) {
      int fl = lp * 256 + t;  // [0,1024)
      int ks = fl >> 7, fr = (fl >> 6) & 1, lane = fl & 63;
      int j = jt * 64 + fr * 32 + (lane & 31);
      int k = ks * 32 + (lane >> 5) * 16;
      const float* src = cbk + (size_t)j * 256 + k;
      int w4[4];
      #pragma unroll
      for (int q4 = 0; q4 < 4; ++q4) {
        float4 v = *(const float4*)(src + q4 * 4);
        int b0 = __float2int_rn(v.x * 2080768.0f);  // 127*16384
        int b1 = __float2int_rn(v.y * 2080768.0f);
        int b2 = __float2int_rn(v.z * 2080768.0f);
        int b3 = __float2int_rn(v.w * 2080768.0f);
        w4[q4] = (b0 & 255) | ((b1 & 255) << 8) | ((b2 & 255) << 16) | ((b3 & 255) << 24);
      }
      int4* dst = (int4*)(cbs8 + (size_t)jt * 16384 + (size_t)fl * 16);
      *dst = make_int4(w4[0], w4[1], w4[2], w4[3]);
    }
  } else if (blk < 384) {
    size_t base = (size_t)(blk - 256) * 2048 + t * 8;
    float4 v0 = *(const float4*)(Wsrc + base);
    float4 v1 = *(const float4*)(Wsrc + base + 4);
    *(ushort4*)(W2 + base) = cvt4(v0);
    *(ushort4*)(W2 + base + 4) = cvt4(v1);
  } else {
    int id = blk - 384;
    int b = id >> 8, c0 = ((id >> 4) & 15) * 64, s0 = (id & 15) * 64;
    int tc = t >> 4, ts = (t & 15) * 4;
    #pragma unroll
    for (int k = 0; k < 4; ++k) {
      float4 v = *(const float4*)(feats + ((size_t)b * 1024 + c0 + tc + k * 16) * 1024 + s0 + ts);
      tile[tc + k * 16][ts] = v.x;
      tile[tc + k * 16][ts + 1] = v.y;
      tile[tc + k * 16][ts + 2] = v.z;
      tile[tc + k * 16][ts + 3] = v.w;
    }
    __syncthreads();
    #pragma unroll
    for (int k = 0; k < 4; ++k) {
      int sr = tc + k * 16;
      float4 v;
      v.x = tile[ts][sr]; v.y = tile[ts + 1][sr];
      v.z = tile[ts + 2][sr]; v.w = tile[ts + 3][sr];
      *(ushort4*)(At + (size_t)(b * 1024 + s0 + sr) * 1024 + c0 + ts) = cvt4(v);
    }
  }
}

// GEMM1: z[i][e] = sum_c feats[i][c]*W[e][c] + b[e] (K=1024 bf16) -> zb [i][256]
// bf16 (for ||z||^2 in k_final) + z8 [i][256] i8 (scale 16, for gemm2).
// BM=BN=64, BK=128, 4 waves 2x2 (wave 32x32), grid (4,128). LDS 2 x 16 KB.
__global__ __launch_bounds__(256, 2)
void k_gemm1(const unsigned short* __restrict__ At, const unsigned short* __restrict__ Bw,
             const float* __restrict__ bias, unsigned short* __restrict__ zb,
             signed char* __restrict__ z8) {
  __shared__ __align__(16) uint8_t lds[2048 * 16];
  uint8_t* ldsA = lds;
  uint8_t* ldsB = lds + 1024 * 16;
  const int t = threadIdx.x, w = t >> 6, l = t & 63;
  const int wy = w >> 1, wx = w & 1, l15 = l & 15, q = l >> 4;
  const int ib = blockIdx.y * 64, eb = blockIdx.x * 64;
  f32x4 acc[2][2] = {};
  for (int kt = 0; kt < 8; ++kt) {
    int c0 = kt * 128;
    __syncthreads();
    #pragma unroll
    for (int r = 0; r < 4; ++r) {
      int P = t + 256 * r;  // kp = P>>6 (0..15), m = P&63; LDS layout [kp][m]
      gl2lds16(At + (size_t)(ib + (P & 63)) * 1024 + c0 + (P >> 6) * 8, ldsA + P * 16);
    }
    #pragma unroll
    for (int r = 0; r < 4; ++r) {
      int P = t + 256 * r;
      gl2lds16(Bw + (size_t)(eb + (P & 63)) * 1024 + c0 + (P >> 6) * 8, ldsB + P * 16);
    }
    __syncthreads();
    #pragma unroll
    for (int s = 0; s < 4; ++s) {
      s16x8 a[2], b[2];
      #pragma unroll
      for (int fr = 0; fr < 2; ++fr)
        a[fr] = *(const s16x8*)(ldsA + ((s * 4 + q) * 64 + wy * 32 + fr * 16 + l15) * 16);
      #pragma unroll
      for (int fc = 0; fc < 2; ++fc)
        b[fc] = *(const s16x8*)(ldsB + ((s * 4 + q) * 64 + wx * 32 + fc * 16 + l15) * 16);
      #pragma unroll
      for (int fr = 0; fr < 2; ++fr)
        #pragma unroll
        for (int fc = 0; fc < 2; ++fc)
          acc[fr][fc] = __builtin_amdgcn_mfma_f32_16x16x32_bf16(a[fr], b[fc], acc[fr][fc], 0, 0, 0);
    }
  }
  #pragma unroll
  for (int fc = 0; fc < 2; ++fc) {
    int e = eb + wx * 32 + fc * 16 + l15;
    float bv = bias[e];
    #pragma unroll
    for (int fr = 0; fr < 2; ++fr)
      #pragma unroll
      for (int r = 0; r < 4; ++r) {
        int i = ib + wy * 32 + fr * 16 + q * 4 + r;
        float zf = acc[fr][fc][r] + bv;
        zb[(size_t)i * 256 + e] = f2bf(zf);
        int qv = __float2int_rn(zf * 16.0f);
        qv = qv > 127 ? 127 : (qv < -127 ? -127 : qv);
        z8[(size_t)i * 256 + e] = (signed char)qv;
      }
  }
}

// GEMM2 + argmax in INT8, 32x32x32 j-stream. A = cbs8 (fragment order),
// B = z8 [8192 i][256] staged in LDS (32 KB). 256 thr / 4 waves, i-tile 128.
// Wave tile 64j x 128i: acc[2][4] = 128 AGPR, launch_bounds(256,2), 8 ks
// steps (K=32 each), unroll 2.
// INT fold: p = (acc<<9) + (511 - slot), slot = js*256 + fr*32 + joff(rg);
// exact monotone (|acc| < 2^22), paired v_max3_i32 = 1.5 VALU/score.
// Winner decoded once per fc -> float bit-encode -> csh/atomicMax unchanged.
__global__ __launch_bounds__(256, 2)
void k_gemm2(const signed char* __restrict__ cbs8, const signed char* __restrict__ z8,
             int* __restrict__ best) {
  __shared__ __align__(16) uint8_t ldsB[32768];  // [kseg 16][i 128][16B]
  __shared__ int csh[4][128];
  const int t = threadIdx.x, w = t >> 6, l = t & 63;
  const int l31 = l & 31, h = l >> 5;
  const int ib = blockIdx.y * 128;
  // stage z8 tile: packet P -> i = P&127, kseg = P>>7 (16B per packet)
  #pragma unroll
  for (int r = 0; r < 8; ++r) {
    int P = t + 256 * r;
    gl2lds16(z8 + (size_t)(ib + (P & 127)) * 256 + (P >> 7) * 16, ldsB + P * 16);
  }
  int ibest[4];
  #pragma unroll
  for (int fc = 0; fc < 4; ++fc) ibest[fc] = (int)0x80000000;
  __syncthreads();
  const uint8_t* bbase = ldsB + (h * 128 + l31) * 16;  // + ks*4096 + fc*512
  #pragma unroll 1
  for (int js = 0; js < 2; ++js) {
    const int jtile = blockIdx.x * 8 + js * 4 + w;  // 64-j tile index
    const uint8_t* abase = (const uint8_t*)cbs8 + (size_t)jtile * 16384 + l * 16;
    i32x16 acc[2][4] = {};  // [fr j-half][fc i-quarter]
    #pragma unroll 2
    for (int ks = 0; ks < 8; ++ks) {
      i32x4 a0 = *(const i32x4*)(abase + (ks * 2) * 1024);
      i32x4 a1 = *(const i32x4*)(abase + (ks * 2 + 1) * 1024);
      i32x4 b0 = *(const i32x4*)(bbase + ks * 4096);
      i32x4 b1 = *(const i32x4*)(bbase + ks * 4096 + 512);
      i32x4 b2 = *(const i32x4*)(bbase + ks * 4096 + 1024);
      i32x4 b3 = *(const i32x4*)(bbase + ks * 4096 + 1536);
      acc[0][0] = __builtin_amdgcn_mfma_i32_32x32x32_i8(a0, b0, acc[0][0], 0, 0, 0);
      acc[1][0] = __builtin_amdgcn_mfma_i32_32x32x32_i8(a1, b0, acc[1][0], 0, 0, 0);
      acc[0][1] = __builtin_amdgcn_mfma_i32_32x32x32_i8(a0, b1, acc[0][1], 0, 0, 0);
      acc[1][1] = __builtin_amdgcn_mfma_i32_32x32x32_i8(a1, b1, acc[1][1], 0, 0, 0);
      acc[0][2] = __builtin_amdgcn_mfma_i32_32x32x32_i8(a0, b2, acc[0][2], 0, 0, 0);
      acc[1][2] = __builtin_amdgcn_mfma_i32_32x32x32_i8(a1, b2, acc[1][2], 0, 0, 0);
      acc[0][3] = __builtin_amdgcn_mfma_i32_32x32x32_i8(a0, b3, acc[0][3], 0, 0, 0);
      acc[1][3] = __builtin_amdgcn_mfma_i32_32x32x32_i8(a1, b3, acc[1][3], 0, 0, 0);
    }
    // int fold: slot = js*256 + fr*32 + ((rg&3)+8*(rg>>2)); code = 511-slot
    const int cbase = 511 - js * 256;
    #pragma unroll
    for (int fc = 0; fc < 4; ++fc) {
      int bb = ibest[fc];
      #pragma unroll
      for (int fr = 0; fr < 2; ++fr) {
        const int c1 = cbase - fr * 32;
        #pragma unroll
        for (int rg = 0; rg < 16; rg += 2) {
          int c0 = c1 - ((rg & 3) + 8 * (rg >> 2));  // rg even; rg+1 -> c0-1
          int p0 = (int)(((unsigned)acc[fr][fc][rg] << 9) + (unsigned)c0);
          int p1 = (int)(((unsigned)acc[fr][fc][rg + 1] << 9) + (unsigned)(c0 - 1));
          bb = max(max(p0, p1), bb);  // v_max3_i32
        }
      }
      ibest[fc] = bb;
    }
  }
  // decode winner per fc -> global float encode; reduce over h; atomicMax.
  const float inv = 1.0f / 33292288.0f;  // 1/(16*127*16384)
  const int jbase = blockIdx.x * 512 + w * 64 + 4 * h;
  #pragma unroll
  for (int fc = 0; fc < 4; ++fc) {
    int p = ibest[fc];
    int accw = p >> 9;               // exact (code >= 0)
    int loc = 511 - (p & 511);       // js*256 + fr*32 + joff
    int j = jbase + loc;
    float s = fmaf((float)accw, inv, 3.0f);
    int gb = (int)(((unsigned)__float_as_int(s) << 14) + (unsigned)(16383 - j));
    int bb = max(gb, __shfl_xor(gb, 32, 64));
    if (l < 32) csh[w][fc * 32 + l31] = bb;
  }
  __syncthreads();
  if (t < 128) {
    int m0 = max(max(csh[0][t], csh[1][t]), max(csh[2][t], csh[3][t]));
    atomicMax(&best[ib + t], m0);
  }
}

// Final: decode best -> idx, ||z||^2 + loss, LDS-staged coalesced gather.
// 256 blocks x 256 thr; block = (b, s0) covering 32 rows.
// Loss: dist_i = ||z_i||^2 - (best>>14)*2^-20; last block writes the scalar.
// Gather: phase A reads codebook rows as 256B bursts -> tile[32][257];
// phase B writes out[b][e][s0+sl] in 128B contiguous runs (pad 257).
__global__ void k_final(const float* __restrict__ cbk, const unsigned short* __restrict__ zb,
                        const int* __restrict__ best, float* __restrict__ lossw,
                        float* __restrict__ out) {
  __shared__ float tile[32][257];
  __shared__ int lidx[32];
  __shared__ float ps[4];
  int blk = blockIdx.x, t = threadIdx.x;
  int b = blk >> 5, s0 = (blk & 31) * 32;
  int gi0 = b * 1024 + s0;
  int r8 = t >> 3, c8 = t & 7;
  int bv = best[gi0 + r8];  // 8 lanes/addr broadcast
  if (t < 32) lidx[t] = 16383 - (best[gi0 + t] & 0x3FFF);
  // ||z||^2: thread (r8,c8) covers 32 bf16 elems of row gi0+r8
  const unsigned short* zrow = zb + (size_t)(gi0 + r8) * 256 + c8 * 32;
  float ss = 0.0f;
  #pragma unroll
  for (int k = 0; k < 32; k += 4) {
    ushort4 v = *(const ushort4*)(zrow + k);
    float a0 = bf2f(v.x), a1 = bf2f(v.y), a2 = bf2f(v.z), a3 = bf2f(v.w);
    ss += a0 * a0 + a1 * a1 + a2 * a2 + a3 * a3;
  }
  ss += __shfl_xor(ss, 1, 64);
  ss += __shfl_xor(ss, 2, 64);
  ss += __shfl_xor(ss, 4, 64);
  float dist = 0.0f;
  if (c8 == 0) dist = ss - (float)(bv >> 14) * (1.0f / 1048576.0f);  // 2*score
  float v = dist;
  #pragma unroll
  for (int m = 32; m; m >>= 1) v += __shfl_down(v, m, 64);
  if ((t & 63) == 0) ps[t >> 6] = v;
  __syncthreads();
  if (t == 0) {
    float part = ps[0] + ps[1] + ps[2] + ps[3];
    atomicAdd(lossw, part);
    __threadfence();
    int cnt = atomicAdd((int*)lossw + 1, 1);
    if (cnt == 255) {
      __threadfence();
      float total = atomicAdd(lossw, 0.0f);
      out[2097152] = 1.25f * total * (1.0f / 2097152.0f);
    }
  }
  // gather (lidx is barrier-protected by the __syncthreads above)
  int w = t >> 6, l = t & 63;
  #pragma unroll
  for (int rr = 0; rr < 8; ++rr) {
    int r = w * 8 + rr;
    const float* src = cbk + (size_t)lidx[r] * 256;
    #pragma unroll
    for (int k = 0; k < 4; ++k)
      tile[r][l + 64 * k] = src[l + 64 * k];
  }
  __syncthreads();
  int sl = t & 31, eg = t >> 5;  // eg 0..7
  size_t ob = (size_t)b * 262144 + s0 + sl;
  #pragma unroll
  for (int k = 0; k < 32; ++k) {
    int e = eg + 8 * k;
    out[ob + (size_t)e * 1024] = tile[sl][e];
  }
}

extern "C" void kernel_launch(void* const* d_in, const int* in_sizes, int n_in,
                              void* d_out, int out_size, void* d_ws, size_t ws_size,
                              hipStream_t stream) {
  const float* feats  = (const float*)d_in[0];
  const float* conv_w = (const float*)d_in[1];
  const float* conv_b = (const float*)d_in[2];
  const float* cbk    = (const float*)d_in[3];
  float* out = (float*)d_out;
  char* ws = (char*)d_ws;
  // workspace layout (bytes), ~28 MB total
  unsigned short* featsT = (unsigned short*)(ws);                  // 16,777,216
  unsigned short* W2     = (unsigned short*)(ws + 16777216);       //    524,288
  signed char*    cbs8   = (signed char*)(ws + 17301504);          //  4,194,304
  unsigned short* zb     = (unsigned short*)(ws + 21495808);       //  4,194,304
  signed char*    z8     = (signed char*)(ws + 25690112);          //  2,097,152
  int*            best   = (int*)(ws + 27787264);                  //     32,768
  float*          lossw  = (float*)(ws + 27820032);                //        256

  k_prep<<<2432, 256, 0, stream>>>(cbk, conv_w, feats, cbs8, W2, featsT, lossw, best);
  k_gemm1<<<dim3(4, 128), 256, 0, stream>>>(featsT, W2, conv_b, zb, z8);
  k_gemm2<<<dim3(32, 64), 256, 0, stream>>>(cbs8, z8, best);
  k_final<<<256, 256, 0, stream>>>(cbk, zb, best, lossw, out);
}